// Round 6
// baseline (837.676 us; speedup 1.0000x reference)
//
#include <hip/hip_runtime.h>
#include <float.h>

#define N_ROWS 65536
#define DIM 256
#define K_CODES 4096
#define MARGIN 3e-3f

typedef __attribute__((ext_vector_type(8))) short short8;   // 8 bf16 (4 VGPR)
typedef __attribute__((ext_vector_type(4))) float f32x4;
typedef __attribute__((ext_vector_type(4))) unsigned int u32x4;

__device__ __forceinline__ unsigned short f2bf(float f) {   // RNE
    unsigned u = __float_as_uint(f);
    return (unsigned short)((u + 0x7FFFu + ((u >> 16) & 1u)) >> 16);
}
__device__ __forceinline__ float bf2f(unsigned short h) {
    return __uint_as_float((unsigned)h << 16);
}

// ===========================================================================
// Shared kernels (np-bit-exact, validated rounds 3-5)
// ===========================================================================
__global__ void k_embsqr(const float* __restrict__ E, float* __restrict__ emb_sqr) {
    int k = blockIdx.x * 256 + threadIdx.x;
    float e0 = E[k];
    float s = __fmul_rn(e0, e0);
    for (int d = 1; d < DIM; ++d) {
        float v = E[(size_t)d * K_CODES + k];
        s = __fadd_rn(s, __fmul_rn(v, v));
    }
    emb_sqr[k] = s;
}

__launch_bounds__(256)
__global__ void k_inpsqr(const float* __restrict__ X, float* __restrict__ S) {
    __shared__ float xs[64][261];
    const int tid = threadIdx.x;
    const int rowBase = blockIdx.x * 64;
    const float4* Xv = (const float4*)(X + (size_t)rowBase * DIM);
#pragma unroll
    for (int it = 0; it < 16; ++it) {
        int lin = it * 256 + tid;
        int r = lin >> 6, c4 = lin & 63;
        float4 v = Xv[lin];
        xs[r][c4 * 4 + 0] = v.x; xs[r][c4 * 4 + 1] = v.y;
        xs[r][c4 * 4 + 2] = v.z; xs[r][c4 * 4 + 3] = v.w;
    }
    __syncthreads();
    if (tid < 64) {
        const float* x = xs[tid];
        float b[2];
#pragma unroll
        for (int h = 0; h < 2; ++h) {
            const float* p = x + h * 128;
            float r[8];
#pragma unroll
            for (int j = 0; j < 8; ++j) r[j] = __fmul_rn(p[j], p[j]);
            for (int i = 8; i < 128; i += 8)
#pragma unroll
                for (int j = 0; j < 8; ++j)
                    r[j] = __fadd_rn(r[j], __fmul_rn(p[i + j], p[i + j]));
            b[h] = __fadd_rn(__fadd_rn(__fadd_rn(r[0], r[1]), __fadd_rn(r[2], r[3])),
                             __fadd_rn(__fadd_rn(r[4], r[5]), __fadd_rn(r[6], r[7])));
        }
        S[rowBase + tid] = __fadd_rn(b[0], b[1]);
    }
}

// ===========================================================================
// k_esplit: E [256][4096] -> ET f32 [4096][256] + EThi/ETlo bf16 [4096][256]
// ===========================================================================
__global__ void k_esplit(const float* __restrict__ E, float* __restrict__ ET,
                         unsigned short* __restrict__ EThi, unsigned short* __restrict__ ETlo) {
    __shared__ float t[32][33];
    const int tx = threadIdx.x & 31, ty = threadIdx.x >> 5;
    const int k0 = blockIdx.x * 32;
    const int d0 = blockIdx.y * 32;
#pragma unroll
    for (int i = 0; i < 32; i += 8)
        t[ty + i][tx] = E[(size_t)(d0 + ty + i) * K_CODES + k0 + tx];
    __syncthreads();
#pragma unroll
    for (int i = 0; i < 32; i += 8) {
        float w = t[tx][ty + i];
        size_t o = (size_t)(k0 + ty + i) * DIM + d0 + tx;
        ET[o] = w;
        unsigned short h = f2bf(w);
        EThi[o] = h;
        ETlo[o] = f2bf(w - bf2f(h));
    }
}

// ===========================================================================
// k_filter v2: 3-term bf16-split MFMA + top-2 + flags.
// Round 6 change: DOUBLE-BUFFERED B slices -> ONE barrier per 32-d slice
// (was two).  LDS: buf0 {Bh@0, Bl@16K}, buf1 {Bh@32K, Bl@48K} = 64 KB.
// Prefetch for slice t+1 issued before the MFMA phase; its vmcnt drain sits
// after 24 MFMAs (~full L2-latency cover).  B-frag LDS offsets hoisted.
// __launch_bounds__(512,4) caps VGPR at 128 to guarantee 2 blocks/CU.
// ===========================================================================
#define FBM 128
#define FBN 128

__launch_bounds__(512, 4)
__global__ void k_filter(const float* __restrict__ X,
                         const unsigned short* __restrict__ EThi,
                         const unsigned short* __restrict__ ETlo,
                         const float* __restrict__ emb_sqr,
                         int* __restrict__ out_idx, int* __restrict__ flagcnt,
                         int* __restrict__ flaglist) {
    __shared__ __align__(16) char lds[65536];

    const int tid = threadIdx.x;
    const int lane = tid & 63;
    const int wid = tid >> 6;
    const int wm = wid & 3;          // row-wave: 32 rows each
    const int wn = wid >> 2;         // col-wave: 64 codes each
    const int rowBase = blockIdx.x * FBM;
    const int l15 = lane & 15, l4 = lane >> 4;

    // ---- prologue: stage X slice per 32-d step, load A-frags to registers
    short8 ah[2][8], al[2][8];
    {
        const int prow = tid >> 2;              // 0..127
        const int pd = (tid & 3) * 8;           // 0,8,16,24
        const int wroff = prow * 128 + ((pd * 2) ^ ((prow & 7) << 4));
#pragma unroll
        for (int ks = 0; ks < 8; ++ks) {
            float4 v0 = *(const float4*)&X[(size_t)(rowBase + prow) * DIM + ks * 32 + pd];
            float4 v1 = *(const float4*)&X[(size_t)(rowBase + prow) * DIM + ks * 32 + pd + 4];
            float f[8] = {v0.x, v0.y, v0.z, v0.w, v1.x, v1.y, v1.z, v1.w};
            unsigned H[4], L[4];
#pragma unroll
            for (int p = 0; p < 4; ++p) {
                float a = f[2 * p], b = f[2 * p + 1];
                unsigned short ha = f2bf(a), hb = f2bf(b);
                float la = a - bf2f(ha), lb = b - bf2f(hb);
                H[p] = (unsigned)ha | ((unsigned)hb << 16);
                L[p] = (unsigned)f2bf(la) | ((unsigned)f2bf(lb) << 16);
            }
            u32x4 Hv = {H[0], H[1], H[2], H[3]};
            u32x4 Lv = {L[0], L[1], L[2], L[3]};
            *(u32x4*)(lds + wroff) = Hv;
            *(u32x4*)(lds + 16384 + wroff) = Lv;
            __syncthreads();
#pragma unroll
            for (int mf = 0; mf < 2; ++mf) {
                int rl = wm * 32 + mf * 16 + l15;
                int off = rl * 128 + ((l4 * 16) ^ ((rl & 7) << 4));
                ah[mf][ks] = *(const short8*)(lds + off);
                al[mf][ks] = *(const short8*)(lds + 16384 + off);
            }
            __syncthreads();
        }
    }

    // ---- per-(mf,r) top-2 state
    float v1r[8], v2r[8];
    int i1r[8];
#pragma unroll
    for (int s = 0; s < 8; ++s) { v1r[s] = FLT_MAX; v2r[s] = FLT_MAX; i1r[s] = 0; }

    // ---- B staging geometry (per-thread, loop-invariant)
    const int bcode = tid >> 2;                 // 0..127
    const int bc = tid & 3;                     // 16B chunk, 8 d each
    const int bwroff = bcode * 128 + ((bc * 16) ^ ((bcode & 7) << 4));
    const size_t tbase = (size_t)bcode * DIM + bc * 8;

    // B-frag read offsets, hoisted (XOR swizzle computed once)
    int boff[4];
#pragma unroll
    for (int nf = 0; nf < 4; ++nf) {
        int cl = wn * 64 + nf * 16 + l15;
        boff[nf] = cl * 128 + ((l4 * 16) ^ ((cl & 7) << 4));
    }

    // stage slice 0 into buf0
    {
        u32x4 gh = *(const u32x4*)&EThi[tbase];
        u32x4 gl = *(const u32x4*)&ETlo[tbase];
        *(u32x4*)(lds + bwroff) = gh;
        *(u32x4*)(lds + 16384 + bwroff) = gl;
    }
    __syncthreads();

    for (int ct = 0; ct < K_CODES / FBN; ++ct) {   // 32 code tiles
        f32x4 acc[2][4];
#pragma unroll
        for (int mf = 0; mf < 2; ++mf)
#pragma unroll
            for (int nf = 0; nf < 4; ++nf) acc[mf][nf] = (f32x4)0.f;

#pragma unroll
        for (int ks = 0; ks < 8; ++ks) {
            const int t = ct * 8 + ks;
            const int tn = (t < 255) ? t + 1 : 255;
            // prefetch slice t+1 to registers (vm drain lands after MFMAs)
            const size_t gsrc = (size_t)(tn >> 3) * (FBN * DIM) + (size_t)(tn & 7) * 32 + tbase;
            u32x4 ph = *(const u32x4*)&EThi[gsrc];
            u32x4 pl = *(const u32x4*)&ETlo[gsrc];

            const char* base = lds + ((t & 1) << 15);
#pragma unroll
            for (int nf = 0; nf < 4; ++nf) {
                short8 bh = *(const short8*)(base + boff[nf]);
                short8 bl = *(const short8*)(base + 16384 + boff[nf]);
#pragma unroll
                for (int mf = 0; mf < 2; ++mf) {
                    acc[mf][nf] = __builtin_amdgcn_mfma_f32_16x16x32_bf16(ah[mf][ks], bh, acc[mf][nf], 0, 0, 0);
                    acc[mf][nf] = __builtin_amdgcn_mfma_f32_16x16x32_bf16(ah[mf][ks], bl, acc[mf][nf], 0, 0, 0);
                    acc[mf][nf] = __builtin_amdgcn_mfma_f32_16x16x32_bf16(al[mf][ks], bh, acc[mf][nf], 0, 0, 0);
                }
            }
            // write next slice into the other buffer (its readers synced at
            // the barrier ending step t-1), then ONE barrier to publish
            char* nb = lds + (((t + 1) & 1) << 15);
            *(u32x4*)(nb + bwroff) = ph;
            *(u32x4*)(nb + 16384 + bwroff) = pl;
            __syncthreads();
        }

        // ---- epilogue: approx distance d~ = emb_sqr - 2*M; top-2 update
#pragma unroll
        for (int nf = 0; nf < 4; ++nf) {
            int col = ct * FBN + wn * 64 + nf * 16 + l15;
            float esv = emb_sqr[col];
#pragma unroll
            for (int mf = 0; mf < 2; ++mf)
#pragma unroll
                for (int r = 0; r < 4; ++r) {
                    float da = __fmaf_rn(-2.f, acc[mf][nf][r], esv);
                    int s = mf * 4 + r;
                    if (da < v1r[s]) { v2r[s] = v1r[s]; v1r[s] = da; i1r[s] = col; }
                    else if (da < v2r[s]) v2r[s] = da;
                }
        }
    }

    // ---- cross-entry reduce: per row 32 entries (2 col-waves x 16 lanes)
    __syncthreads();
    float* v1s = (float*)lds;                  // [128][33] 16.9 KB
    int*   i1s = (int*)(lds + 16896);
    float* v2s = (float*)(lds + 33792);
#pragma unroll
    for (int mf = 0; mf < 2; ++mf)
#pragma unroll
        for (int r = 0; r < 4; ++r) {
            int rl = wm * 32 + mf * 16 + l4 * 4 + r;
            int e = wn * 16 + l15;
            v1s[rl * 33 + e] = v1r[mf * 4 + r];
            i1s[rl * 33 + e] = i1r[mf * 4 + r];
            v2s[rl * 33 + e] = v2r[mf * 4 + r];
        }
    __syncthreads();
    if (tid < FBM) {
        float bv1 = v1s[tid * 33], bv2 = v2s[tid * 33];
        int bi = i1s[tid * 33];
#pragma unroll
        for (int e = 1; e < 32; ++e) {
            float v = v1s[tid * 33 + e], w = v2s[tid * 33 + e];
            int ix = i1s[tid * 33 + e];
            if (v < bv1 || (v == bv1 && ix < bi)) {
                bv2 = fminf(bv1, w); bv1 = v; bi = ix;
            } else {
                bv2 = fminf(bv2, v);
            }
        }
        out_idx[rowBase + tid] = bi;
        if (bv2 - bv1 < MARGIN) {
            int p = atomicAdd(flagcnt, 1);
            flaglist[p] = rowBase + tid;
        }
    }
}

// ===========================================================================
// k_fixup32: np-bit-exact full rescan for flagged rows (round-3 arithmetic)
// ===========================================================================
__launch_bounds__(256)
__global__ void k_fixup32(const float* __restrict__ X, const float* __restrict__ E,
                          const float* __restrict__ emb_sqr, const float* __restrict__ S,
                          const int* __restrict__ flagcnt, const int* __restrict__ flaglist,
                          int* __restrict__ out_idx) {
    __shared__ float xs[DIM];
    __shared__ float rv[256];
    __shared__ int ri[256];
    const int tid = threadIdx.x;
    const int cnt = *flagcnt;
    for (int f = blockIdx.x; f < cnt; f += gridDim.x) {
        const int row = flaglist[f];
        xs[tid] = X[(size_t)row * DIM + tid];
        __syncthreads();
        const float Sr = S[row];
        float acc[16];
#pragma unroll
        for (int j = 0; j < 16; ++j) acc[j] = 0.f;
        for (int d = 0; d < DIM; ++d) {
            float xv = xs[d];
            const float* Ed = &E[(size_t)d * K_CODES + tid];
#pragma unroll
            for (int j = 0; j < 16; ++j)
                acc[j] = __fmaf_rn(xv, Ed[j * 256], acc[j]);
        }
        float bv = FLT_MAX;
        int bk = 0;
#pragma unroll
        for (int j = 0; j < 16; ++j) {
            int k = tid + 256 * j;   // ascending within thread
            float dist = __fadd_rn(__fsub_rn(Sr, __fmul_rn(2.f, acc[j])), emb_sqr[k]);
            if (dist < bv) { bv = dist; bk = k; }
        }
        rv[tid] = bv; ri[tid] = bk;
        __syncthreads();
        for (int s = 128; s > 0; s >>= 1) {
            if (tid < s) {
                float v = rv[tid + s]; int k2 = ri[tid + s];
                if (v < rv[tid] || (v == rv[tid] && k2 < ri[tid])) { rv[tid] = v; ri[tid] = k2; }
            }
            __syncthreads();
        }
        if (tid == 0) out_idx[row] = ri[0];
        __syncthreads();
    }
}

// ===========================================================================
// Fallback fp32 argmin (round-4, validated) for small-ws case
// ===========================================================================
#define BM 64
#define BN 256
#define DCHUNK 8
#define XS_LD 260

#define FMA8(a, b1, b2, accrow)                                       \
    do {                                                              \
        accrow[0] = __fmaf_rn((a), (b1).x, accrow[0]);                \
        accrow[1] = __fmaf_rn((a), (b1).y, accrow[1]);                \
        accrow[2] = __fmaf_rn((a), (b1).z, accrow[2]);                \
        accrow[3] = __fmaf_rn((a), (b1).w, accrow[3]);                \
        accrow[4] = __fmaf_rn((a), (b2).x, accrow[4]);                \
        accrow[5] = __fmaf_rn((a), (b2).y, accrow[5]);                \
        accrow[6] = __fmaf_rn((a), (b2).z, accrow[6]);                \
        accrow[7] = __fmaf_rn((a), (b2).w, accrow[7]);                \
    } while (0)

__launch_bounds__(256, 2)
__global__ void k_argmin(const float* __restrict__ X, const float* __restrict__ E,
                         const float* __restrict__ emb_sqr, const float* __restrict__ S,
                         int* __restrict__ out_idx) {
    __shared__ float Xs[BM][XS_LD];
    __shared__ float Es[DCHUNK][BN];
    const int tid = threadIdx.x;
    const int tx = tid & 31;
    const int ty = tid >> 5;
    const int rowBase = blockIdx.x * BM;
    const int r0 = ty * 8;
    {
        const float4* Xv = (const float4*)(X + (size_t)rowBase * DIM);
#pragma unroll
        for (int it = 0; it < 16; ++it) {
            int lin = it * 256 + tid;
            int r = lin >> 6, c4 = lin & 63;
            float4 v = Xv[lin];
            *(float4*)&Xs[r][c4 * 4] = v;
        }
    }
    float Srow[8];
#pragma unroll
    for (int i = 0; i < 8; ++i) Srow[i] = S[rowBase + r0 + i];
    float best[8];
    int bidx[8];
#pragma unroll
    for (int i = 0; i < 8; ++i) { best[i] = FLT_MAX; bidx[i] = 0; }
    for (int ct = 0; ct < K_CODES / BN; ++ct) {
        const int cbase = ct * BN;
        float acc[8][8];
#pragma unroll
        for (int i = 0; i < 8; ++i)
#pragma unroll
            for (int j = 0; j < 8; ++j) acc[i][j] = 0.f;
        for (int dc = 0; dc < DIM / DCHUNK; ++dc) {
            __syncthreads();
#pragma unroll
            for (int it = 0; it < 2; ++it) {
                int lin = it * 256 + tid;
                int r = lin >> 6, c4 = lin & 63;
                float4 v = *(const float4*)&E[(size_t)(dc * DCHUNK + r) * K_CODES + cbase + c4 * 4];
                *(float4*)&Es[r][c4 * 4] = v;
            }
            __syncthreads();
            const int db = dc * DCHUNK;
#pragma unroll
            for (int kk = 0; kk < DCHUNK; kk += 4) {
                float4 a4[8];
#pragma unroll
                for (int i = 0; i < 8; ++i)
                    a4[i] = *(const float4*)&Xs[r0 + i][db + kk];
                float4 bA[4], bB[4];
#pragma unroll
                for (int t = 0; t < 4; ++t) {
                    bA[t] = *(const float4*)&Es[kk + t][tx * 4];
                    bB[t] = *(const float4*)&Es[kk + t][128 + tx * 4];
                }
#pragma unroll
                for (int i = 0; i < 8; ++i) {
                    float4 av = a4[i];
                    FMA8(av.x, bA[0], bB[0], acc[i]);
                    FMA8(av.y, bA[1], bB[1], acc[i]);
                    FMA8(av.z, bA[2], bB[2], acc[i]);
                    FMA8(av.w, bA[3], bB[3], acc[i]);
                }
            }
        }
        float es[8];
#pragma unroll
        for (int j = 0; j < 4; ++j) es[j]     = emb_sqr[cbase + tx * 4 + j];
#pragma unroll
        for (int j = 0; j < 4; ++j) es[4 + j] = emb_sqr[cbase + 128 + tx * 4 + j];
#pragma unroll
        for (int i = 0; i < 8; ++i) {
#pragma unroll
            for (int j = 0; j < 8; ++j) {
                float d = __fadd_rn(__fsub_rn(Srow[i], __fmul_rn(2.f, acc[i][j])), es[j]);
                int cidx = cbase + ((j < 4) ? (tx * 4 + j) : (128 + tx * 4 + (j - 4)));
                if (d < best[i]) { best[i] = d; bidx[i] = cidx; }
            }
        }
    }
    __syncthreads();
    float* rv1 = &Xs[0][0];
    int*   ri1 = (int*)(rv1 + 2048);
#pragma unroll
    for (int i = 0; i < 8; ++i) {
        rv1[(r0 + i) * 32 + tx] = best[i];
        ri1[(r0 + i) * 32 + tx] = bidx[i];
    }
    __syncthreads();
    if (tid < BM) {
        float bv = rv1[tid * 32];
        int bi = ri1[tid * 32];
#pragma unroll
        for (int t = 1; t < 32; ++t) {
            float v = rv1[tid * 32 + t];
            int ix = ri1[tid * 32 + t];
            if (v < bv || (v == bv && ix < bi)) { bv = v; bi = ix; }
        }
        out_idx[rowBase + tid] = bi;
    }
}

// ===========================================================================
// Gather + loss
// ===========================================================================
__global__ void k_gather_et(const float* __restrict__ X, const float* __restrict__ ET,
                            const int* __restrict__ idx, float* __restrict__ out,
                            float* __restrict__ partials) {
    const int tid = threadIdx.x;
    const int total4 = N_ROWS * DIM / 4;
    float lsum = 0.f;
    for (int g = blockIdx.x * 256 + tid; g < total4; g += 2048 * 256) {
        int row = g >> 6;
        int d4 = g & 63;
        int k = idx[row];
        float4 z = *(const float4*)&X[(size_t)g * 4];
        float4 q = *(const float4*)&ET[(size_t)k * DIM + d4 * 4];
        float dx = __fsub_rn(q.x, z.x), dy = __fsub_rn(q.y, z.y);
        float dz = __fsub_rn(q.z, z.z), dw = __fsub_rn(q.w, z.w);
        float4 o;
        o.x = __fadd_rn(z.x, dx); o.y = __fadd_rn(z.y, dy);
        o.z = __fadd_rn(z.z, dz); o.w = __fadd_rn(z.w, dw);
        *(float4*)&out[(size_t)g * 4] = o;
        lsum += dx * dx + dy * dy + dz * dz + dw * dw;
    }
    __shared__ float red[256];
    red[tid] = lsum;
    __syncthreads();
    for (int s = 128; s > 0; s >>= 1) {
        if (tid < s) red[tid] += red[tid + s];
        __syncthreads();
    }
    if (tid == 0) partials[blockIdx.x] = red[0];
}

__global__ void k_gather_e(const float* __restrict__ X, const float* __restrict__ E,
                           const int* __restrict__ idx, float* __restrict__ out,
                           float* __restrict__ partials) {
    const int tid = threadIdx.x;
    const int total4 = N_ROWS * DIM / 4;
    float lsum = 0.f;
    for (int g = blockIdx.x * 256 + tid; g < total4; g += 2048 * 256) {
        int row = g >> 6;
        int d4 = g & 63;
        int k = idx[row];
        float4 z = *(const float4*)&X[(size_t)g * 4];
        float4 q;
        q.x = E[(size_t)(d4 * 4 + 0) * K_CODES + k];
        q.y = E[(size_t)(d4 * 4 + 1) * K_CODES + k];
        q.z = E[(size_t)(d4 * 4 + 2) * K_CODES + k];
        q.w = E[(size_t)(d4 * 4 + 3) * K_CODES + k];
        float dx = __fsub_rn(q.x, z.x), dy = __fsub_rn(q.y, z.y);
        float dz = __fsub_rn(q.z, z.z), dw = __fsub_rn(q.w, z.w);
        float4 o;
        o.x = __fadd_rn(z.x, dx); o.y = __fadd_rn(z.y, dy);
        o.z = __fadd_rn(z.z, dz); o.w = __fadd_rn(z.w, dw);
        *(float4*)&out[(size_t)g * 4] = o;
        lsum += dx * dx + dy * dy + dz * dz + dw * dw;
    }
    __shared__ float red[256];
    red[tid] = lsum;
    __syncthreads();
    for (int s = 128; s > 0; s >>= 1) {
        if (tid < s) red[tid] += red[tid + s];
        __syncthreads();
    }
    if (tid == 0) partials[blockIdx.x] = red[0];
}

__global__ void k_loss(const float* __restrict__ partials, float* __restrict__ out_loss) {
    __shared__ float red[256];
    const int tid = threadIdx.x;
    float s = 0.f;
    for (int i = tid; i < 2048; i += 256) s += partials[i];
    red[tid] = s;
    __syncthreads();
    for (int st = 128; st > 0; st >>= 1) {
        if (tid < st) red[tid] += red[tid + st];
        __syncthreads();
    }
    if (tid == 0) out_loss[0] = 1.25f * red[0] / 16777216.0f;
}

// ===========================================================================
extern "C" void kernel_launch(void* const* d_in, const int* in_sizes, int n_in,
                              void* d_out, int out_size, void* d_ws, size_t ws_size,
                              hipStream_t stream) {
    (void)in_sizes; (void)n_in; (void)out_size;
    const float* X = (const float*)d_in[0];   // z_latents [65536][256]
    const float* E = (const float*)d_in[1];   // embeddings [256][4096]
    float* out = (float*)d_out;

    char* ws = (char*)d_ws;
    int*   idx      = (int*)ws;                         // @0        256 KB
    float* emb_sqr  = (float*)(ws + 262144);            // @262144   16 KB
    float* S        = (float*)(ws + 278528);            // @278528   256 KB
    float* partials = (float*)(ws + 540672);            // @540672   8 KB
    int*   flagcnt  = (int*)(ws + 548864);              // @548864   256 B
    int*   flaglist = (int*)(ws + 549120);              // @549120   256 KB
    float* ET       = (float*)(ws + 811264);            // @811264   4 MB
    unsigned short* EThi = (unsigned short*)(ws + 5005568);  // 2 MB
    unsigned short* ETlo = (unsigned short*)(ws + 7102720);  // 2 MB
    const size_t WS_NEED = 9199872;

    k_embsqr<<<K_CODES / 256, 256, 0, stream>>>(E, emb_sqr);
    k_inpsqr<<<N_ROWS / 64, 256, 0, stream>>>(X, S);

    if (ws_size >= WS_NEED) {
        hipMemsetAsync(flagcnt, 0, 4, stream);
        k_esplit<<<dim3(K_CODES / 32, DIM / 32), 256, 0, stream>>>(E, ET, EThi, ETlo);
        k_filter<<<N_ROWS / FBM, 512, 0, stream>>>(X, EThi, ETlo, emb_sqr, idx, flagcnt, flaglist);
        k_fixup32<<<512, 256, 0, stream>>>(X, E, emb_sqr, S, flagcnt, flaglist, idx);
        k_gather_et<<<2048, 256, 0, stream>>>(X, ET, idx, out, partials);
    } else {
        k_argmin<<<N_ROWS / BM, 256, 0, stream>>>(X, E, emb_sqr, S, idx);
        k_gather_e<<<2048, 256, 0, stream>>>(X, E, idx, out, partials);
    }
    k_loss<<<1, 256, 0, stream>>>(partials, out + (size_t)N_ROWS * DIM);
}

// Round 7
// 723.698 us; speedup vs baseline: 1.1575x; 1.1575x over previous
//
#include <hip/hip_runtime.h>
#include <float.h>

#define N_ROWS 65536
#define DIM 256
#define K_CODES 4096
#define MARGIN 3e-3f

typedef __attribute__((ext_vector_type(8))) short short8;   // 8 bf16 (4 VGPR)
typedef __attribute__((ext_vector_type(4))) float f32x4;
typedef __attribute__((ext_vector_type(4))) unsigned int u32x4;

__device__ __forceinline__ unsigned short f2bf(float f) {   // RNE
    unsigned u = __float_as_uint(f);
    return (unsigned short)((u + 0x7FFFu + ((u >> 16) & 1u)) >> 16);
}
__device__ __forceinline__ float bf2f(unsigned short h) {
    return __uint_as_float((unsigned)h << 16);
}

// ===========================================================================
// Shared kernels (np-bit-exact, validated rounds 3-6)
// ===========================================================================
__global__ void k_embsqr(const float* __restrict__ E, float* __restrict__ emb_sqr) {
    int k = blockIdx.x * 256 + threadIdx.x;
    float e0 = E[k];
    float s = __fmul_rn(e0, e0);
    for (int d = 1; d < DIM; ++d) {
        float v = E[(size_t)d * K_CODES + k];
        s = __fadd_rn(s, __fmul_rn(v, v));
    }
    emb_sqr[k] = s;
}

__launch_bounds__(256)
__global__ void k_inpsqr(const float* __restrict__ X, float* __restrict__ S) {
    __shared__ float xs[64][261];
    const int tid = threadIdx.x;
    const int rowBase = blockIdx.x * 64;
    const float4* Xv = (const float4*)(X + (size_t)rowBase * DIM);
#pragma unroll
    for (int it = 0; it < 16; ++it) {
        int lin = it * 256 + tid;
        int r = lin >> 6, c4 = lin & 63;
        float4 v = Xv[lin];
        xs[r][c4 * 4 + 0] = v.x; xs[r][c4 * 4 + 1] = v.y;
        xs[r][c4 * 4 + 2] = v.z; xs[r][c4 * 4 + 3] = v.w;
    }
    __syncthreads();
    if (tid < 64) {
        const float* x = xs[tid];
        float b[2];
#pragma unroll
        for (int h = 0; h < 2; ++h) {
            const float* p = x + h * 128;
            float r[8];
#pragma unroll
            for (int j = 0; j < 8; ++j) r[j] = __fmul_rn(p[j], p[j]);
            for (int i = 8; i < 128; i += 8)
#pragma unroll
                for (int j = 0; j < 8; ++j)
                    r[j] = __fadd_rn(r[j], __fmul_rn(p[i + j], p[i + j]));
            b[h] = __fadd_rn(__fadd_rn(__fadd_rn(r[0], r[1]), __fadd_rn(r[2], r[3])),
                             __fadd_rn(__fadd_rn(r[4], r[5]), __fadd_rn(r[6], r[7])));
        }
        S[rowBase + tid] = __fadd_rn(b[0], b[1]);
    }
}

// ===========================================================================
// k_esplit: E [256][4096] -> ET f32 [4096][256] + EThi/ETlo bf16 [4096][256]
// ===========================================================================
__global__ void k_esplit(const float* __restrict__ E, float* __restrict__ ET,
                         unsigned short* __restrict__ EThi, unsigned short* __restrict__ ETlo) {
    __shared__ float t[32][33];
    const int tx = threadIdx.x & 31, ty = threadIdx.x >> 5;
    const int k0 = blockIdx.x * 32;
    const int d0 = blockIdx.y * 32;
#pragma unroll
    for (int i = 0; i < 32; i += 8)
        t[ty + i][tx] = E[(size_t)(d0 + ty + i) * K_CODES + k0 + tx];
    __syncthreads();
#pragma unroll
    for (int i = 0; i < 32; i += 8) {
        float w = t[tx][ty + i];
        size_t o = (size_t)(k0 + ty + i) * DIM + d0 + tx;
        ET[o] = w;
        unsigned short h = f2bf(w);
        EThi[o] = h;
        ETlo[o] = f2bf(w - bf2f(h));
    }
}

// ===========================================================================
// k_filter v3: 3-term bf16-split MFMA + top-2 + flags.
// Double-buffered B slices, ONE barrier per 32-d slice (round-6 structure)
// at the round-5-proven register budget: __launch_bounds__(512,2).
// (512,4) is infeasible: A-frags alone need 128 regs -> r6 spilled to
// scratch, 1.9 GB HBM traffic. 2 waves/SIMD is the operating point.
// ===========================================================================
#define FBM 128
#define FBN 128

__launch_bounds__(512, 2)
__global__ void k_filter(const float* __restrict__ X,
                         const unsigned short* __restrict__ EThi,
                         const unsigned short* __restrict__ ETlo,
                         const float* __restrict__ emb_sqr,
                         int* __restrict__ out_idx, int* __restrict__ flagcnt,
                         int* __restrict__ flaglist) {
    __shared__ __align__(16) char lds[65536];

    const int tid = threadIdx.x;
    const int lane = tid & 63;
    const int wid = tid >> 6;
    const int wm = wid & 3;          // row-wave: 32 rows each
    const int wn = wid >> 2;         // col-wave: 64 codes each
    const int rowBase = blockIdx.x * FBM;
    const int l15 = lane & 15, l4 = lane >> 4;

    // ---- prologue: stage X slice per 32-d step, load A-frags to registers
    short8 ah[2][8], al[2][8];
    {
        const int prow = tid >> 2;              // 0..127
        const int pd = (tid & 3) * 8;           // 0,8,16,24
        const int wroff = prow * 128 + ((pd * 2) ^ ((prow & 7) << 4));
#pragma unroll
        for (int ks = 0; ks < 8; ++ks) {
            float4 v0 = *(const float4*)&X[(size_t)(rowBase + prow) * DIM + ks * 32 + pd];
            float4 v1 = *(const float4*)&X[(size_t)(rowBase + prow) * DIM + ks * 32 + pd + 4];
            float f[8] = {v0.x, v0.y, v0.z, v0.w, v1.x, v1.y, v1.z, v1.w};
            unsigned H[4], L[4];
#pragma unroll
            for (int p = 0; p < 4; ++p) {
                float a = f[2 * p], b = f[2 * p + 1];
                unsigned short ha = f2bf(a), hb = f2bf(b);
                float la = a - bf2f(ha), lb = b - bf2f(hb);
                H[p] = (unsigned)ha | ((unsigned)hb << 16);
                L[p] = (unsigned)f2bf(la) | ((unsigned)f2bf(lb) << 16);
            }
            u32x4 Hv = {H[0], H[1], H[2], H[3]};
            u32x4 Lv = {L[0], L[1], L[2], L[3]};
            *(u32x4*)(lds + wroff) = Hv;
            *(u32x4*)(lds + 16384 + wroff) = Lv;
            __syncthreads();
#pragma unroll
            for (int mf = 0; mf < 2; ++mf) {
                int rl = wm * 32 + mf * 16 + l15;
                int off = rl * 128 + ((l4 * 16) ^ ((rl & 7) << 4));
                ah[mf][ks] = *(const short8*)(lds + off);
                al[mf][ks] = *(const short8*)(lds + 16384 + off);
            }
            __syncthreads();
        }
    }

    // ---- per-(mf,r) top-2 state
    float v1r[8], v2r[8];
    int i1r[8];
#pragma unroll
    for (int s = 0; s < 8; ++s) { v1r[s] = FLT_MAX; v2r[s] = FLT_MAX; i1r[s] = 0; }

    // ---- B staging geometry (per-thread, loop-invariant)
    const int bcode = tid >> 2;                 // 0..127
    const int bc = tid & 3;                     // 16B chunk, 8 d each
    const int bwroff = bcode * 128 + ((bc * 16) ^ ((bcode & 7) << 4));
    const size_t tbase = (size_t)bcode * DIM + bc * 8;

    // B-frag read offsets, hoisted (XOR swizzle computed once)
    int boff[4];
#pragma unroll
    for (int nf = 0; nf < 4; ++nf) {
        int cl = wn * 64 + nf * 16 + l15;
        boff[nf] = cl * 128 + ((l4 * 16) ^ ((cl & 7) << 4));
    }

    // stage slice 0 into buf0
    {
        u32x4 gh = *(const u32x4*)&EThi[tbase];
        u32x4 gl = *(const u32x4*)&ETlo[tbase];
        *(u32x4*)(lds + bwroff) = gh;
        *(u32x4*)(lds + 16384 + bwroff) = gl;
    }
    __syncthreads();

    for (int ct = 0; ct < K_CODES / FBN; ++ct) {   // 32 code tiles
        f32x4 acc[2][4];
#pragma unroll
        for (int mf = 0; mf < 2; ++mf)
#pragma unroll
            for (int nf = 0; nf < 4; ++nf) acc[mf][nf] = (f32x4)0.f;

#pragma unroll
        for (int ks = 0; ks < 8; ++ks) {
            const int t = ct * 8 + ks;
            const int tn = (t < 255) ? t + 1 : 255;
            // prefetch slice t+1 to registers (vm drain lands after MFMAs)
            const size_t gsrc = (size_t)(tn >> 3) * (FBN * DIM) + (size_t)(tn & 7) * 32 + tbase;
            u32x4 ph = *(const u32x4*)&EThi[gsrc];
            u32x4 pl = *(const u32x4*)&ETlo[gsrc];

            const char* base = lds + ((t & 1) << 15);
#pragma unroll
            for (int nf = 0; nf < 4; ++nf) {
                short8 bh = *(const short8*)(base + boff[nf]);
                short8 bl = *(const short8*)(base + 16384 + boff[nf]);
#pragma unroll
                for (int mf = 0; mf < 2; ++mf) {
                    acc[mf][nf] = __builtin_amdgcn_mfma_f32_16x16x32_bf16(ah[mf][ks], bh, acc[mf][nf], 0, 0, 0);
                    acc[mf][nf] = __builtin_amdgcn_mfma_f32_16x16x32_bf16(ah[mf][ks], bl, acc[mf][nf], 0, 0, 0);
                    acc[mf][nf] = __builtin_amdgcn_mfma_f32_16x16x32_bf16(al[mf][ks], bh, acc[mf][nf], 0, 0, 0);
                }
            }
            // write next slice into the other buffer (its readers synced at
            // the barrier ending step t-1), then ONE barrier to publish
            char* nb = lds + (((t + 1) & 1) << 15);
            *(u32x4*)(nb + bwroff) = ph;
            *(u32x4*)(nb + 16384 + bwroff) = pl;
            __syncthreads();
        }

        // ---- epilogue: approx distance d~ = emb_sqr - 2*M; top-2 update
#pragma unroll
        for (int nf = 0; nf < 4; ++nf) {
            int col = ct * FBN + wn * 64 + nf * 16 + l15;
            float esv = emb_sqr[col];
#pragma unroll
            for (int mf = 0; mf < 2; ++mf)
#pragma unroll
                for (int r = 0; r < 4; ++r) {
                    float da = __fmaf_rn(-2.f, acc[mf][nf][r], esv);
                    int s = mf * 4 + r;
                    if (da < v1r[s]) { v2r[s] = v1r[s]; v1r[s] = da; i1r[s] = col; }
                    else if (da < v2r[s]) v2r[s] = da;
                }
        }
    }

    // ---- cross-entry reduce: per row 32 entries (2 col-waves x 16 lanes)
    __syncthreads();
    float* v1s = (float*)lds;                  // [128][33] 16.9 KB
    int*   i1s = (int*)(lds + 16896);
    float* v2s = (float*)(lds + 33792);
#pragma unroll
    for (int mf = 0; mf < 2; ++mf)
#pragma unroll
        for (int r = 0; r < 4; ++r) {
            int rl = wm * 32 + mf * 16 + l4 * 4 + r;
            int e = wn * 16 + l15;
            v1s[rl * 33 + e] = v1r[mf * 4 + r];
            i1s[rl * 33 + e] = i1r[mf * 4 + r];
            v2s[rl * 33 + e] = v2r[mf * 4 + r];
        }
    __syncthreads();
    if (tid < FBM) {
        float bv1 = v1s[tid * 33], bv2 = v2s[tid * 33];
        int bi = i1s[tid * 33];
#pragma unroll
        for (int e = 1; e < 32; ++e) {
            float v = v1s[tid * 33 + e], w = v2s[tid * 33 + e];
            int ix = i1s[tid * 33 + e];
            if (v < bv1 || (v == bv1 && ix < bi)) {
                bv2 = fminf(bv1, w); bv1 = v; bi = ix;
            } else {
                bv2 = fminf(bv2, v);
            }
        }
        out_idx[rowBase + tid] = bi;
        if (bv2 - bv1 < MARGIN) {
            int p = atomicAdd(flagcnt, 1);
            flaglist[p] = rowBase + tid;
        }
    }
}

// ===========================================================================
// k_fixup32: np-bit-exact full rescan for flagged rows (round-3 arithmetic)
// ===========================================================================
__launch_bounds__(256)
__global__ void k_fixup32(const float* __restrict__ X, const float* __restrict__ E,
                          const float* __restrict__ emb_sqr, const float* __restrict__ S,
                          const int* __restrict__ flagcnt, const int* __restrict__ flaglist,
                          int* __restrict__ out_idx) {
    __shared__ float xs[DIM];
    __shared__ float rv[256];
    __shared__ int ri[256];
    const int tid = threadIdx.x;
    const int cnt = *flagcnt;
    for (int f = blockIdx.x; f < cnt; f += gridDim.x) {
        const int row = flaglist[f];
        xs[tid] = X[(size_t)row * DIM + tid];
        __syncthreads();
        const float Sr = S[row];
        float acc[16];
#pragma unroll
        for (int j = 0; j < 16; ++j) acc[j] = 0.f;
        for (int d = 0; d < DIM; ++d) {
            float xv = xs[d];
            const float* Ed = &E[(size_t)d * K_CODES + tid];
#pragma unroll
            for (int j = 0; j < 16; ++j)
                acc[j] = __fmaf_rn(xv, Ed[j * 256], acc[j]);
        }
        float bv = FLT_MAX;
        int bk = 0;
#pragma unroll
        for (int j = 0; j < 16; ++j) {
            int k = tid + 256 * j;   // ascending within thread
            float dist = __fadd_rn(__fsub_rn(Sr, __fmul_rn(2.f, acc[j])), emb_sqr[k]);
            if (dist < bv) { bv = dist; bk = k; }
        }
        rv[tid] = bv; ri[tid] = bk;
        __syncthreads();
        for (int s = 128; s > 0; s >>= 1) {
            if (tid < s) {
                float v = rv[tid + s]; int k2 = ri[tid + s];
                if (v < rv[tid] || (v == rv[tid] && k2 < ri[tid])) { rv[tid] = v; ri[tid] = k2; }
            }
            __syncthreads();
        }
        if (tid == 0) out_idx[row] = ri[0];
        __syncthreads();
    }
}

// ===========================================================================
// Fallback fp32 argmin (round-4, validated) for small-ws case
// ===========================================================================
#define BM 64
#define BN 256
#define DCHUNK 8
#define XS_LD 260

#define FMA8(a, b1, b2, accrow)                                       \
    do {                                                              \
        accrow[0] = __fmaf_rn((a), (b1).x, accrow[0]);                \
        accrow[1] = __fmaf_rn((a), (b1).y, accrow[1]);                \
        accrow[2] = __fmaf_rn((a), (b1).z, accrow[2]);                \
        accrow[3] = __fmaf_rn((a), (b1).w, accrow[3]);                \
        accrow[4] = __fmaf_rn((a), (b2).x, accrow[4]);                \
        accrow[5] = __fmaf_rn((a), (b2).y, accrow[5]);                \
        accrow[6] = __fmaf_rn((a), (b2).z, accrow[6]);                \
        accrow[7] = __fmaf_rn((a), (b2).w, accrow[7]);                \
    } while (0)

__launch_bounds__(256, 2)
__global__ void k_argmin(const float* __restrict__ X, const float* __restrict__ E,
                         const float* __restrict__ emb_sqr, const float* __restrict__ S,
                         int* __restrict__ out_idx) {
    __shared__ float Xs[BM][XS_LD];
    __shared__ float Es[DCHUNK][BN];
    const int tid = threadIdx.x;
    const int tx = tid & 31;
    const int ty = tid >> 5;
    const int rowBase = blockIdx.x * BM;
    const int r0 = ty * 8;
    {
        const float4* Xv = (const float4*)(X + (size_t)rowBase * DIM);
#pragma unroll
        for (int it = 0; it < 16; ++it) {
            int lin = it * 256 + tid;
            int r = lin >> 6, c4 = lin & 63;
            float4 v = Xv[lin];
            *(float4*)&Xs[r][c4 * 4] = v;
        }
    }
    float Srow[8];
#pragma unroll
    for (int i = 0; i < 8; ++i) Srow[i] = S[rowBase + r0 + i];
    float best[8];
    int bidx[8];
#pragma unroll
    for (int i = 0; i < 8; ++i) { best[i] = FLT_MAX; bidx[i] = 0; }
    for (int ct = 0; ct < K_CODES / BN; ++ct) {
        const int cbase = ct * BN;
        float acc[8][8];
#pragma unroll
        for (int i = 0; i < 8; ++i)
#pragma unroll
            for (int j = 0; j < 8; ++j) acc[i][j] = 0.f;
        for (int dc = 0; dc < DIM / DCHUNK; ++dc) {
            __syncthreads();
#pragma unroll
            for (int it = 0; it < 2; ++it) {
                int lin = it * 256 + tid;
                int r = lin >> 6, c4 = lin & 63;
                float4 v = *(const float4*)&E[(size_t)(dc * DCHUNK + r) * K_CODES + cbase + c4 * 4];
                *(float4*)&Es[r][c4 * 4] = v;
            }
            __syncthreads();
            const int db = dc * DCHUNK;
#pragma unroll
            for (int kk = 0; kk < DCHUNK; kk += 4) {
                float4 a4[8];
#pragma unroll
                for (int i = 0; i < 8; ++i)
                    a4[i] = *(const float4*)&Xs[r0 + i][db + kk];
                float4 bA[4], bB[4];
#pragma unroll
                for (int t = 0; t < 4; ++t) {
                    bA[t] = *(const float4*)&Es[kk + t][tx * 4];
                    bB[t] = *(const float4*)&Es[kk + t][128 + tx * 4];
                }
#pragma unroll
                for (int i = 0; i < 8; ++i) {
                    float4 av = a4[i];
                    FMA8(av.x, bA[0], bB[0], acc[i]);
                    FMA8(av.y, bA[1], bB[1], acc[i]);
                    FMA8(av.z, bA[2], bB[2], acc[i]);
                    FMA8(av.w, bA[3], bB[3], acc[i]);
                }
            }
        }
        float es[8];
#pragma unroll
        for (int j = 0; j < 4; ++j) es[j]     = emb_sqr[cbase + tx * 4 + j];
#pragma unroll
        for (int j = 0; j < 4; ++j) es[4 + j] = emb_sqr[cbase + 128 + tx * 4 + j];
#pragma unroll
        for (int i = 0; i < 8; ++i) {
#pragma unroll
            for (int j = 0; j < 8; ++j) {
                float d = __fadd_rn(__fsub_rn(Srow[i], __fmul_rn(2.f, acc[i][j])), es[j]);
                int cidx = cbase + ((j < 4) ? (tx * 4 + j) : (128 + tx * 4 + (j - 4)));
                if (d < best[i]) { best[i] = d; bidx[i] = cidx; }
            }
        }
    }
    __syncthreads();
    float* rv1 = &Xs[0][0];
    int*   ri1 = (int*)(rv1 + 2048);
#pragma unroll
    for (int i = 0; i < 8; ++i) {
        rv1[(r0 + i) * 32 + tx] = best[i];
        ri1[(r0 + i) * 32 + tx] = bidx[i];
    }
    __syncthreads();
    if (tid < BM) {
        float bv = rv1[tid * 32];
        int bi = ri1[tid * 32];
#pragma unroll
        for (int t = 1; t < 32; ++t) {
            float v = rv1[tid * 32 + t];
            int ix = ri1[tid * 32 + t];
            if (v < bv || (v == bv && ix < bi)) { bv = v; bi = ix; }
        }
        out_idx[rowBase + tid] = bi;
    }
}

// ===========================================================================
// Gather + loss
// ===========================================================================
__global__ void k_gather_et(const float* __restrict__ X, const float* __restrict__ ET,
                            const int* __restrict__ idx, float* __restrict__ out,
                            float* __restrict__ partials) {
    const int tid = threadIdx.x;
    const int total4 = N_ROWS * DIM / 4;
    float lsum = 0.f;
    for (int g = blockIdx.x * 256 + tid; g < total4; g += 2048 * 256) {
        int row = g >> 6;
        int d4 = g & 63;
        int k = idx[row];
        float4 z = *(const float4*)&X[(size_t)g * 4];
        float4 q = *(const float4*)&ET[(size_t)k * DIM + d4 * 4];
        float dx = __fsub_rn(q.x, z.x), dy = __fsub_rn(q.y, z.y);
        float dz = __fsub_rn(q.z, z.z), dw = __fsub_rn(q.w, z.w);
        float4 o;
        o.x = __fadd_rn(z.x, dx); o.y = __fadd_rn(z.y, dy);
        o.z = __fadd_rn(z.z, dz); o.w = __fadd_rn(z.w, dw);
        *(float4*)&out[(size_t)g * 4] = o;
        lsum += dx * dx + dy * dy + dz * dz + dw * dw;
    }
    __shared__ float red[256];
    red[tid] = lsum;
    __syncthreads();
    for (int s = 128; s > 0; s >>= 1) {
        if (tid < s) red[tid] += red[tid + s];
        __syncthreads();
    }
    if (tid == 0) partials[blockIdx.x] = red[0];
}

__global__ void k_gather_e(const float* __restrict__ X, const float* __restrict__ E,
                           const int* __restrict__ idx, float* __restrict__ out,
                           float* __restrict__ partials) {
    const int tid = threadIdx.x;
    const int total4 = N_ROWS * DIM / 4;
    float lsum = 0.f;
    for (int g = blockIdx.x * 256 + tid; g < total4; g += 2048 * 256) {
        int row = g >> 6;
        int d4 = g & 63;
        int k = idx[row];
        float4 z = *(const float4*)&X[(size_t)g * 4];
        float4 q;
        q.x = E[(size_t)(d4 * 4 + 0) * K_CODES + k];
        q.y = E[(size_t)(d4 * 4 + 1) * K_CODES + k];
        q.z = E[(size_t)(d4 * 4 + 2) * K_CODES + k];
        q.w = E[(size_t)(d4 * 4 + 3) * K_CODES + k];
        float dx = __fsub_rn(q.x, z.x), dy = __fsub_rn(q.y, z.y);
        float dz = __fsub_rn(q.z, z.z), dw = __fsub_rn(q.w, z.w);
        float4 o;
        o.x = __fadd_rn(z.x, dx); o.y = __fadd_rn(z.y, dy);
        o.z = __fadd_rn(z.z, dz); o.w = __fadd_rn(z.w, dw);
        *(float4*)&out[(size_t)g * 4] = o;
        lsum += dx * dx + dy * dy + dz * dz + dw * dw;
    }
    __shared__ float red[256];
    red[tid] = lsum;
    __syncthreads();
    for (int s = 128; s > 0; s >>= 1) {
        if (tid < s) red[tid] += red[tid + s];
        __syncthreads();
    }
    if (tid == 0) partials[blockIdx.x] = red[0];
}

__global__ void k_loss(const float* __restrict__ partials, float* __restrict__ out_loss) {
    __shared__ float red[256];
    const int tid = threadIdx.x;
    float s = 0.f;
    for (int i = tid; i < 2048; i += 256) s += partials[i];
    red[tid] = s;
    __syncthreads();
    for (int st = 128; st > 0; st >>= 1) {
        if (tid < st) red[tid] += red[tid + st];
        __syncthreads();
    }
    if (tid == 0) out_loss[0] = 1.25f * red[0] / 16777216.0f;
}

// ===========================================================================
extern "C" void kernel_launch(void* const* d_in, const int* in_sizes, int n_in,
                              void* d_out, int out_size, void* d_ws, size_t ws_size,
                              hipStream_t stream) {
    (void)in_sizes; (void)n_in; (void)out_size;
    const float* X = (const float*)d_in[0];   // z_latents [65536][256]
    const float* E = (const float*)d_in[1];   // embeddings [256][4096]
    float* out = (float*)d_out;

    char* ws = (char*)d_ws;
    int*   idx      = (int*)ws;                         // @0        256 KB
    float* emb_sqr  = (float*)(ws + 262144);            // @262144   16 KB
    float* S        = (float*)(ws + 278528);            // @278528   256 KB
    float* partials = (float*)(ws + 540672);            // @540672   8 KB
    int*   flagcnt  = (int*)(ws + 548864);              // @548864   256 B
    int*   flaglist = (int*)(ws + 549120);              // @549120   256 KB
    float* ET       = (float*)(ws + 811264);            // @811264   4 MB
    unsigned short* EThi = (unsigned short*)(ws + 5005568);  // 2 MB
    unsigned short* ETlo = (unsigned short*)(ws + 7102720);  // 2 MB
    const size_t WS_NEED = 9199872;

    k_embsqr<<<K_CODES / 256, 256, 0, stream>>>(E, emb_sqr);
    k_inpsqr<<<N_ROWS / 64, 256, 0, stream>>>(X, S);

    if (ws_size >= WS_NEED) {
        hipMemsetAsync(flagcnt, 0, 4, stream);
        k_esplit<<<dim3(K_CODES / 32, DIM / 32), 256, 0, stream>>>(E, ET, EThi, ETlo);
        k_filter<<<N_ROWS / FBM, 512, 0, stream>>>(X, EThi, ETlo, emb_sqr, idx, flagcnt, flaglist);
        k_fixup32<<<512, 256, 0, stream>>>(X, E, emb_sqr, S, flagcnt, flaglist, idx);
        k_gather_et<<<2048, 256, 0, stream>>>(X, ET, idx, out, partials);
    } else {
        k_argmin<<<N_ROWS / BM, 256, 0, stream>>>(X, E, emb_sqr, S, idx);
        k_gather_e<<<2048, 256, 0, stream>>>(X, E, idx, out, partials);
    }
    k_loss<<<1, 256, 0, stream>>>(partials, out + (size_t)N_ROWS * DIM);
}

// Round 8
// 681.493 us; speedup vs baseline: 1.2292x; 1.0619x over previous
//
#include <hip/hip_runtime.h>
#include <float.h>

#define N_ROWS 65536
#define DIM 256
#define K_CODES 4096
#define MARGIN 3e-3f

typedef __attribute__((ext_vector_type(8))) short short8;   // 8 bf16 (4 VGPR)
typedef __attribute__((ext_vector_type(4))) float f32x4;
typedef __attribute__((ext_vector_type(4))) unsigned int u32x4;

__device__ __forceinline__ unsigned short f2bf(float f) {   // RNE
    unsigned u = __float_as_uint(f);
    return (unsigned short)((u + 0x7FFFu + ((u >> 16) & 1u)) >> 16);
}
__device__ __forceinline__ float bf2f(unsigned short h) {
    return __uint_as_float((unsigned)h << 16);
}

// async global->LDS DMA, 16B per lane; LDS dest = wave-uniform base + lane*16
__device__ __forceinline__ void gload16(const void* gsrc, void* ldst) {
    __builtin_amdgcn_global_load_lds(
        (__attribute__((address_space(1))) unsigned int*)gsrc,
        (__attribute__((address_space(3))) unsigned int*)ldst,
        16, 0, 0);
}

// ===========================================================================
// Shared kernels (np-bit-exact, validated rounds 3-7)
// ===========================================================================
__global__ void k_embsqr(const float* __restrict__ E, float* __restrict__ emb_sqr) {
    int k = blockIdx.x * 256 + threadIdx.x;
    float e0 = E[k];
    float s = __fmul_rn(e0, e0);
    for (int d = 1; d < DIM; ++d) {
        float v = E[(size_t)d * K_CODES + k];
        s = __fadd_rn(s, __fmul_rn(v, v));
    }
    emb_sqr[k] = s;
}

__launch_bounds__(256)
__global__ void k_inpsqr(const float* __restrict__ X, float* __restrict__ S) {
    __shared__ float xs[64][261];
    const int tid = threadIdx.x;
    const int rowBase = blockIdx.x * 64;
    const float4* Xv = (const float4*)(X + (size_t)rowBase * DIM);
#pragma unroll
    for (int it = 0; it < 16; ++it) {
        int lin = it * 256 + tid;
        int r = lin >> 6, c4 = lin & 63;
        float4 v = Xv[lin];
        xs[r][c4 * 4 + 0] = v.x; xs[r][c4 * 4 + 1] = v.y;
        xs[r][c4 * 4 + 2] = v.z; xs[r][c4 * 4 + 3] = v.w;
    }
    __syncthreads();
    if (tid < 64) {
        const float* x = xs[tid];
        float b[2];
#pragma unroll
        for (int h = 0; h < 2; ++h) {
            const float* p = x + h * 128;
            float r[8];
#pragma unroll
            for (int j = 0; j < 8; ++j) r[j] = __fmul_rn(p[j], p[j]);
            for (int i = 8; i < 128; i += 8)
#pragma unroll
                for (int j = 0; j < 8; ++j)
                    r[j] = __fadd_rn(r[j], __fmul_rn(p[i + j], p[i + j]));
            b[h] = __fadd_rn(__fadd_rn(__fadd_rn(r[0], r[1]), __fadd_rn(r[2], r[3])),
                             __fadd_rn(__fadd_rn(r[4], r[5]), __fadd_rn(r[6], r[7])));
        }
        S[rowBase + tid] = __fadd_rn(b[0], b[1]);
    }
}

// ===========================================================================
// k_esplit: E [256][4096] -> ET f32 [4096][256] + EThi/ETlo bf16 [4096][256]
// ===========================================================================
__global__ void k_esplit(const float* __restrict__ E, float* __restrict__ ET,
                         unsigned short* __restrict__ EThi, unsigned short* __restrict__ ETlo) {
    __shared__ float t[32][33];
    const int tx = threadIdx.x & 31, ty = threadIdx.x >> 5;
    const int k0 = blockIdx.x * 32;
    const int d0 = blockIdx.y * 32;
#pragma unroll
    for (int i = 0; i < 32; i += 8)
        t[ty + i][tx] = E[(size_t)(d0 + ty + i) * K_CODES + k0 + tx];
    __syncthreads();
#pragma unroll
    for (int i = 0; i < 32; i += 8) {
        float w = t[tx][ty + i];
        size_t o = (size_t)(k0 + ty + i) * DIM + d0 + tx;
        ET[o] = w;
        unsigned short h = f2bf(w);
        EThi[o] = h;
        ETlo[o] = f2bf(w - bf2f(h));
    }
}

// ===========================================================================
// k_filter v4: 3-term bf16-split MFMA + top-2 + flags.
// Round 8 change: B staging via global_load_lds (16B DMA), double-buffered,
// one barrier per 32-d slice. gload_lds writes linearly -> the SOURCE address
// is inverse-swizzled (chunk c = c' ^ ((r>>1)&3), lane-only) so the linear
// LDS write lands swizzled; reads apply the same involution (rule #21).
// LDS: buf0 {Bh@0,Bl@8K}, buf1 {Bh@16K,Bl@24K} = 32KB; reduce scratch 50688B.
// ===========================================================================
#define FBM 128
#define FBN 128

__launch_bounds__(512, 2)
__global__ void k_filter(const float* __restrict__ X,
                         const unsigned short* __restrict__ EThi,
                         const unsigned short* __restrict__ ETlo,
                         const float* __restrict__ emb_sqr,
                         int* __restrict__ out_idx, int* __restrict__ flagcnt,
                         int* __restrict__ flaglist) {
    __shared__ __align__(16) char lds[50688];

    const int tid = threadIdx.x;
    const int lane = tid & 63;
    const int wid = tid >> 6;
    const int wm = wid & 3;          // row-wave: 32 rows each
    const int wn = wid >> 2;         // col-wave: 64 codes each
    const int rowBase = blockIdx.x * FBM;
    const int l15 = lane & 15, l4 = lane >> 4;

    // ---- prologue: stage X slice per 32-d step, load A-frags to registers
    short8 ah[2][8], al[2][8];
    {
        const int prow = tid >> 2;              // 0..127
        const int pd = (tid & 3) * 8;           // 0,8,16,24
        const int wroff = prow * 128 + ((pd * 2) ^ ((prow & 7) << 4));
#pragma unroll
        for (int ks = 0; ks < 8; ++ks) {
            float4 v0 = *(const float4*)&X[(size_t)(rowBase + prow) * DIM + ks * 32 + pd];
            float4 v1 = *(const float4*)&X[(size_t)(rowBase + prow) * DIM + ks * 32 + pd + 4];
            float f[8] = {v0.x, v0.y, v0.z, v0.w, v1.x, v1.y, v1.z, v1.w};
            unsigned H[4], L[4];
#pragma unroll
            for (int p = 0; p < 4; ++p) {
                float a = f[2 * p], b = f[2 * p + 1];
                unsigned short ha = f2bf(a), hb = f2bf(b);
                float la = a - bf2f(ha), lb = b - bf2f(hb);
                H[p] = (unsigned)ha | ((unsigned)hb << 16);
                L[p] = (unsigned)f2bf(la) | ((unsigned)f2bf(lb) << 16);
            }
            u32x4 Hv = {H[0], H[1], H[2], H[3]};
            u32x4 Lv = {L[0], L[1], L[2], L[3]};
            *(u32x4*)(lds + wroff) = Hv;
            *(u32x4*)(lds + 16384 + wroff) = Lv;
            __syncthreads();
#pragma unroll
            for (int mf = 0; mf < 2; ++mf) {
                int rl = wm * 32 + mf * 16 + l15;
                int off = rl * 128 + ((l4 * 16) ^ ((rl & 7) << 4));
                ah[mf][ks] = *(const short8*)(lds + off);
                al[mf][ks] = *(const short8*)(lds + 16384 + off);
            }
            __syncthreads();
        }
    }

    // ---- per-(mf,r) top-2 state
    float v1r[8], v2r[8];
    int i1r[8];
#pragma unroll
    for (int s = 0; s < 8; ++s) { v1r[s] = FLT_MAX; v2r[s] = FLT_MAX; i1r[s] = 0; }

    // ---- gload_lds source geometry (per-lane, loop-invariant):
    // LDS slot of this lane = wave_base + lane*16  ->  (code r, chunk c')
    //   r = wid*16 + (lane>>2),  c' = lane&3
    // inverse swizzle: global chunk c = c' ^ ((r>>1)&3) = (lane&3)^((lane>>3)&3)
    const int gr = (wid << 4) + (lane >> 2);
    const int gc = (lane & 3) ^ ((lane >> 3) & 3);
    const size_t goff = (size_t)gr * DIM + gc * 8;      // u16 elements
    char* const wdst = lds + (wid << 10);               // wave's 1KB LDS chunk

    // ---- B-frag read offsets (swizzled), hoisted
    int boff[4];
#pragma unroll
    for (int nf = 0; nf < 4; ++nf) {
        int cl = wn * 64 + nf * 16 + l15;
        boff[nf] = cl * 64 + ((l4 ^ ((cl >> 1) & 3)) << 4);
    }

    // ---- stage slice 0 into buf0
    gload16(EThi + goff, wdst);
    gload16(ETlo + goff, wdst + 8192);
    __syncthreads();

    for (int ct = 0; ct < K_CODES / FBN; ++ct) {   // 32 code tiles
        f32x4 acc[2][4];
#pragma unroll
        for (int mf = 0; mf < 2; ++mf)
#pragma unroll
            for (int nf = 0; nf < 4; ++nf) acc[mf][nf] = (f32x4)0.f;

#pragma unroll
        for (int ks = 0; ks < 8; ++ks) {
            const int t = ct * 8 + ks;
            // issue DMA for slice t+1 into the other buffer
            if (t < 255) {
                const int tn = t + 1;
                const size_t go = (size_t)(tn >> 3) * (FBN * DIM) + (size_t)(tn & 7) * 32 + goff;
                char* nb = ((tn & 1) ? (lds + 16384) : lds) + (wid << 10);
                gload16(EThi + go, nb);
                gload16(ETlo + go, nb + 8192);
            }
            // consume current slice
            const char* base = lds + ((t & 1) << 14);
#pragma unroll
            for (int nf = 0; nf < 4; ++nf) {
                short8 bh = *(const short8*)(base + boff[nf]);
                short8 bl = *(const short8*)(base + 8192 + boff[nf]);
#pragma unroll
                for (int mf = 0; mf < 2; ++mf) {
                    acc[mf][nf] = __builtin_amdgcn_mfma_f32_16x16x32_bf16(ah[mf][ks], bh, acc[mf][nf], 0, 0, 0);
                    acc[mf][nf] = __builtin_amdgcn_mfma_f32_16x16x32_bf16(ah[mf][ks], bl, acc[mf][nf], 0, 0, 0);
                    acc[mf][nf] = __builtin_amdgcn_mfma_f32_16x16x32_bf16(al[mf][ks], bh, acc[mf][nf], 0, 0, 0);
                }
            }
            __syncthreads();   // drains DMA (vmcnt) + LDS reads (lgkm)
        }

        // ---- epilogue: approx distance d~ = emb_sqr - 2*M; top-2 update
#pragma unroll
        for (int nf = 0; nf < 4; ++nf) {
            int col = ct * FBN + wn * 64 + nf * 16 + l15;
            float esv = emb_sqr[col];
#pragma unroll
            for (int mf = 0; mf < 2; ++mf)
#pragma unroll
                for (int r = 0; r < 4; ++r) {
                    float da = __fmaf_rn(-2.f, acc[mf][nf][r], esv);
                    int s = mf * 4 + r;
                    if (da < v1r[s]) { v2r[s] = v1r[s]; v1r[s] = da; i1r[s] = col; }
                    else if (da < v2r[s]) v2r[s] = da;
                }
        }
    }

    // ---- cross-entry reduce: per row 32 entries (2 col-waves x 16 lanes)
    __syncthreads();
    float* v1s = (float*)lds;                  // [128][33] 16.9 KB
    int*   i1s = (int*)(lds + 16896);
    float* v2s = (float*)(lds + 33792);
#pragma unroll
    for (int mf = 0; mf < 2; ++mf)
#pragma unroll
        for (int r = 0; r < 4; ++r) {
            int rl = wm * 32 + mf * 16 + l4 * 4 + r;
            int e = wn * 16 + l15;
            v1s[rl * 33 + e] = v1r[mf * 4 + r];
            i1s[rl * 33 + e] = i1r[mf * 4 + r];
            v2s[rl * 33 + e] = v2r[mf * 4 + r];
        }
    __syncthreads();
    if (tid < FBM) {
        float bv1 = v1s[tid * 33], bv2 = v2s[tid * 33];
        int bi = i1s[tid * 33];
#pragma unroll
        for (int e = 1; e < 32; ++e) {
            float v = v1s[tid * 33 + e], w = v2s[tid * 33 + e];
            int ix = i1s[tid * 33 + e];
            if (v < bv1 || (v == bv1 && ix < bi)) {
                bv2 = fminf(bv1, w); bv1 = v; bi = ix;
            } else {
                bv2 = fminf(bv2, v);
            }
        }
        out_idx[rowBase + tid] = bi;
        if (bv2 - bv1 < MARGIN) {
            int p = atomicAdd(flagcnt, 1);
            flaglist[p] = rowBase + tid;
        }
    }
}

// ===========================================================================
// k_fixup32: np-bit-exact full rescan for flagged rows (round-3 arithmetic)
// ===========================================================================
__launch_bounds__(256)
__global__ void k_fixup32(const float* __restrict__ X, const float* __restrict__ E,
                          const float* __restrict__ emb_sqr, const float* __restrict__ S,
                          const int* __restrict__ flagcnt, const int* __restrict__ flaglist,
                          int* __restrict__ out_idx) {
    __shared__ float xs[DIM];
    __shared__ float rv[256];
    __shared__ int ri[256];
    const int tid = threadIdx.x;
    const int cnt = *flagcnt;
    for (int f = blockIdx.x; f < cnt; f += gridDim.x) {
        const int row = flaglist[f];
        xs[tid] = X[(size_t)row * DIM + tid];
        __syncthreads();
        const float Sr = S[row];
        float acc[16];
#pragma unroll
        for (int j = 0; j < 16; ++j) acc[j] = 0.f;
        for (int d = 0; d < DIM; ++d) {
            float xv = xs[d];
            const float* Ed = &E[(size_t)d * K_CODES + tid];
#pragma unroll
            for (int j = 0; j < 16; ++j)
                acc[j] = __fmaf_rn(xv, Ed[j * 256], acc[j]);
        }
        float bv = FLT_MAX;
        int bk = 0;
#pragma unroll
        for (int j = 0; j < 16; ++j) {
            int k = tid + 256 * j;   // ascending within thread
            float dist = __fadd_rn(__fsub_rn(Sr, __fmul_rn(2.f, acc[j])), emb_sqr[k]);
            if (dist < bv) { bv = dist; bk = k; }
        }
        rv[tid] = bv; ri[tid] = bk;
        __syncthreads();
        for (int s = 128; s > 0; s >>= 1) {
            if (tid < s) {
                float v = rv[tid + s]; int k2 = ri[tid + s];
                if (v < rv[tid] || (v == rv[tid] && k2 < ri[tid])) { rv[tid] = v; ri[tid] = k2; }
            }
            __syncthreads();
        }
        if (tid == 0) out_idx[row] = ri[0];
        __syncthreads();
    }
}

// ===========================================================================
// Fallback fp32 argmin (round-4, validated) for small-ws case
// ===========================================================================
#define BM 64
#define BN 256
#define DCHUNK 8
#define XS_LD 260

#define FMA8(a, b1, b2, accrow)                                       \
    do {                                                              \
        accrow[0] = __fmaf_rn((a), (b1).x, accrow[0]);                \
        accrow[1] = __fmaf_rn((a), (b1).y, accrow[1]);                \
        accrow[2] = __fmaf_rn((a), (b1).z, accrow[2]);                \
        accrow[3] = __fmaf_rn((a), (b1).w, accrow[3]);                \
        accrow[4] = __fmaf_rn((a), (b2).x, accrow[4]);                \
        accrow[5] = __fmaf_rn((a), (b2).y, accrow[5]);                \
        accrow[6] = __fmaf_rn((a), (b2).z, accrow[6]);                \
        accrow[7] = __fmaf_rn((a), (b2).w, accrow[7]);                \
    } while (0)

__launch_bounds__(256, 2)
__global__ void k_argmin(const float* __restrict__ X, const float* __restrict__ E,
                         const float* __restrict__ emb_sqr, const float* __restrict__ S,
                         int* __restrict__ out_idx) {
    __shared__ float Xs[BM][XS_LD];
    __shared__ float Es[DCHUNK][BN];
    const int tid = threadIdx.x;
    const int tx = tid & 31;
    const int ty = tid >> 5;
    const int rowBase = blockIdx.x * BM;
    const int r0 = ty * 8;
    {
        const float4* Xv = (const float4*)(X + (size_t)rowBase * DIM);
#pragma unroll
        for (int it = 0; it < 16; ++it) {
            int lin = it * 256 + tid;
            int r = lin >> 6, c4 = lin & 63;
            float4 v = Xv[lin];
            *(float4*)&Xs[r][c4 * 4] = v;
        }
    }
    float Srow[8];
#pragma unroll
    for (int i = 0; i < 8; ++i) Srow[i] = S[rowBase + r0 + i];
    float best[8];
    int bidx[8];
#pragma unroll
    for (int i = 0; i < 8; ++i) { best[i] = FLT_MAX; bidx[i] = 0; }
    for (int ct = 0; ct < K_CODES / BN; ++ct) {
        const int cbase = ct * BN;
        float acc[8][8];
#pragma unroll
        for (int i = 0; i < 8; ++i)
#pragma unroll
            for (int j = 0; j < 8; ++j) acc[i][j] = 0.f;
        for (int dc = 0; dc < DIM / DCHUNK; ++dc) {
            __syncthreads();
#pragma unroll
            for (int it = 0; it < 2; ++it) {
                int lin = it * 256 + tid;
                int r = lin >> 6, c4 = lin & 63;
                float4 v = *(const float4*)&E[(size_t)(dc * DCHUNK + r) * K_CODES + cbase + c4 * 4];
                *(float4*)&Es[r][c4 * 4] = v;
            }
            __syncthreads();
            const int db = dc * DCHUNK;
#pragma unroll
            for (int kk = 0; kk < DCHUNK; kk += 4) {
                float4 a4[8];
#pragma unroll
                for (int i = 0; i < 8; ++i)
                    a4[i] = *(const float4*)&Xs[r0 + i][db + kk];
                float4 bA[4], bB[4];
#pragma unroll
                for (int t = 0; t < 4; ++t) {
                    bA[t] = *(const float4*)&Es[kk + t][tx * 4];
                    bB[t] = *(const float4*)&Es[kk + t][128 + tx * 4];
                }
#pragma unroll
                for (int i = 0; i < 8; ++i) {
                    float4 av = a4[i];
                    FMA8(av.x, bA[0], bB[0], acc[i]);
                    FMA8(av.y, bA[1], bB[1], acc[i]);
                    FMA8(av.z, bA[2], bB[2], acc[i]);
                    FMA8(av.w, bA[3], bB[3], acc[i]);
                }
            }
        }
        float es[8];
#pragma unroll
        for (int j = 0; j < 4; ++j) es[j]     = emb_sqr[cbase + tx * 4 + j];
#pragma unroll
        for (int j = 0; j < 4; ++j) es[4 + j] = emb_sqr[cbase + 128 + tx * 4 + j];
#pragma unroll
        for (int i = 0; i < 8; ++i) {
#pragma unroll
            for (int j = 0; j < 8; ++j) {
                float d = __fadd_rn(__fsub_rn(Srow[i], __fmul_rn(2.f, acc[i][j])), es[j]);
                int cidx = cbase + ((j < 4) ? (tx * 4 + j) : (128 + tx * 4 + (j - 4)));
                if (d < best[i]) { best[i] = d; bidx[i] = cidx; }
            }
        }
    }
    __syncthreads();
    float* rv1 = &Xs[0][0];
    int*   ri1 = (int*)(rv1 + 2048);
#pragma unroll
    for (int i = 0; i < 8; ++i) {
        rv1[(r0 + i) * 32 + tx] = best[i];
        ri1[(r0 + i) * 32 + tx] = bidx[i];
    }
    __syncthreads();
    if (tid < BM) {
        float bv = rv1[tid * 32];
        int bi = ri1[tid * 32];
#pragma unroll
        for (int t = 1; t < 32; ++t) {
            float v = rv1[tid * 32 + t];
            int ix = ri1[tid * 32 + t];
            if (v < bv || (v == bv && ix < bi)) { bv = v; bi = ix; }
        }
        out_idx[rowBase + tid] = bi;
    }
}

// ===========================================================================
// Gather + loss
// ===========================================================================
__global__ void k_gather_et(const float* __restrict__ X, const float* __restrict__ ET,
                            const int* __restrict__ idx, float* __restrict__ out,
                            float* __restrict__ partials) {
    const int tid = threadIdx.x;
    const int total4 = N_ROWS * DIM / 4;
    float lsum = 0.f;
    for (int g = blockIdx.x * 256 + tid; g < total4; g += 2048 * 256) {
        int row = g >> 6;
        int d4 = g & 63;
        int k = idx[row];
        float4 z = *(const float4*)&X[(size_t)g * 4];
        float4 q = *(const float4*)&ET[(size_t)k * DIM + d4 * 4];
        float dx = __fsub_rn(q.x, z.x), dy = __fsub_rn(q.y, z.y);
        float dz = __fsub_rn(q.z, z.z), dw = __fsub_rn(q.w, z.w);
        float4 o;
        o.x = __fadd_rn(z.x, dx); o.y = __fadd_rn(z.y, dy);
        o.z = __fadd_rn(z.z, dz); o.w = __fadd_rn(z.w, dw);
        *(float4*)&out[(size_t)g * 4] = o;
        lsum += dx * dx + dy * dy + dz * dz + dw * dw;
    }
    __shared__ float red[256];
    red[tid] = lsum;
    __syncthreads();
    for (int s = 128; s > 0; s >>= 1) {
        if (tid < s) red[tid] += red[tid + s];
        __syncthreads();
    }
    if (tid == 0) partials[blockIdx.x] = red[0];
}

__global__ void k_gather_e(const float* __restrict__ X, const float* __restrict__ E,
                           const int* __restrict__ idx, float* __restrict__ out,
                           float* __restrict__ partials) {
    const int tid = threadIdx.x;
    const int total4 = N_ROWS * DIM / 4;
    float lsum = 0.f;
    for (int g = blockIdx.x * 256 + tid; g < total4; g += 2048 * 256) {
        int row = g >> 6;
        int d4 = g & 63;
        int k = idx[row];
        float4 z = *(const float4*)&X[(size_t)g * 4];
        float4 q;
        q.x = E[(size_t)(d4 * 4 + 0) * K_CODES + k];
        q.y = E[(size_t)(d4 * 4 + 1) * K_CODES + k];
        q.z = E[(size_t)(d4 * 4 + 2) * K_CODES + k];
        q.w = E[(size_t)(d4 * 4 + 3) * K_CODES + k];
        float dx = __fsub_rn(q.x, z.x), dy = __fsub_rn(q.y, z.y);
        float dz = __fsub_rn(q.z, z.z), dw = __fsub_rn(q.w, z.w);
        float4 o;
        o.x = __fadd_rn(z.x, dx); o.y = __fadd_rn(z.y, dy);
        o.z = __fadd_rn(z.z, dz); o.w = __fadd_rn(z.w, dw);
        *(float4*)&out[(size_t)g * 4] = o;
        lsum += dx * dx + dy * dy + dz * dz + dw * dw;
    }
    __shared__ float red[256];
    red[tid] = lsum;
    __syncthreads();
    for (int s = 128; s > 0; s >>= 1) {
        if (tid < s) red[tid] += red[tid + s];
        __syncthreads();
    }
    if (tid == 0) partials[blockIdx.x] = red[0];
}

__global__ void k_loss(const float* __restrict__ partials, float* __restrict__ out_loss) {
    __shared__ float red[256];
    const int tid = threadIdx.x;
    float s = 0.f;
    for (int i = tid; i < 2048; i += 256) s += partials[i];
    red[tid] = s;
    __syncthreads();
    for (int st = 128; st > 0; st >>= 1) {
        if (tid < st) red[tid] += red[tid + st];
        __syncthreads();
    }
    if (tid == 0) out_loss[0] = 1.25f * red[0] / 16777216.0f;
}

// ===========================================================================
extern "C" void kernel_launch(void* const* d_in, const int* in_sizes, int n_in,
                              void* d_out, int out_size, void* d_ws, size_t ws_size,
                              hipStream_t stream) {
    (void)in_sizes; (void)n_in; (void)out_size;
    const float* X = (const float*)d_in[0];   // z_latents [65536][256]
    const float* E = (const float*)d_in[1];   // embeddings [256][4096]
    float* out = (float*)d_out;

    char* ws = (char*)d_ws;
    int*   idx      = (int*)ws;                         // @0        256 KB
    float* emb_sqr  = (float*)(ws + 262144);            // @262144   16 KB
    float* S        = (float*)(ws + 278528);            // @278528   256 KB
    float* partials = (float*)(ws + 540672);            // @540672   8 KB
    int*   flagcnt  = (int*)(ws + 548864);              // @548864   256 B
    int*   flaglist = (int*)(ws + 549120);              // @549120   256 KB
    float* ET       = (float*)(ws + 811264);            // @811264   4 MB
    unsigned short* EThi = (unsigned short*)(ws + 5005568);  // 2 MB
    unsigned short* ETlo = (unsigned short*)(ws + 7102720);  // 2 MB
    const size_t WS_NEED = 9199872;

    k_embsqr<<<K_CODES / 256, 256, 0, stream>>>(E, emb_sqr);
    k_inpsqr<<<N_ROWS / 64, 256, 0, stream>>>(X, S);

    if (ws_size >= WS_NEED) {
        hipMemsetAsync(flagcnt, 0, 4, stream);
        k_esplit<<<dim3(K_CODES / 32, DIM / 32), 256, 0, stream>>>(E, ET, EThi, ETlo);
        k_filter<<<N_ROWS / FBM, 512, 0, stream>>>(X, EThi, ETlo, emb_sqr, idx, flagcnt, flaglist);
        k_fixup32<<<512, 256, 0, stream>>>(X, E, emb_sqr, S, flagcnt, flaglist, idx);
        k_gather_et<<<2048, 256, 0, stream>>>(X, ET, idx, out, partials);
    } else {
        k_argmin<<<N_ROWS / BM, 256, 0, stream>>>(X, E, emb_sqr, S, idx);
        k_gather_e<<<2048, 256, 0, stream>>>(X, E, idx, out, partials);
    }
    k_loss<<<1, 256, 0, stream>>>(partials, out + (size_t)N_ROWS * DIM);
}

// Round 9
// 648.020 us; speedup vs baseline: 1.2927x; 1.0517x over previous
//
#include <hip/hip_runtime.h>
#include <float.h>

#define N_ROWS 65536
#define DIM 256
#define K_CODES 4096
#define MARGIN 3e-3f

typedef __attribute__((ext_vector_type(8))) short short8;   // 8 bf16 (4 VGPR)
typedef __attribute__((ext_vector_type(4))) float f32x4;
typedef __attribute__((ext_vector_type(4))) unsigned int u32x4;

__device__ __forceinline__ unsigned short f2bf(float f) {   // RNE
    unsigned u = __float_as_uint(f);
    return (unsigned short)((u + 0x7FFFu + ((u >> 16) & 1u)) >> 16);
}
__device__ __forceinline__ float bf2f(unsigned short h) {
    return __uint_as_float((unsigned)h << 16);
}

// async global->LDS DMA, 16B per lane; LDS dest = wave-uniform base + lane*16
__device__ __forceinline__ void gload16(const void* gsrc, void* ldst) {
    __builtin_amdgcn_global_load_lds(
        (__attribute__((address_space(1))) unsigned int*)gsrc,
        (__attribute__((address_space(3))) unsigned int*)ldst,
        16, 0, 0);
}

// ===========================================================================
// Shared kernels (np-bit-exact, validated rounds 3-8)
// ===========================================================================
__global__ void k_embsqr(const float* __restrict__ E, float* __restrict__ emb_sqr) {
    int k = blockIdx.x * 256 + threadIdx.x;
    float e0 = E[k];
    float s = __fmul_rn(e0, e0);
    for (int d = 1; d < DIM; ++d) {
        float v = E[(size_t)d * K_CODES + k];
        s = __fadd_rn(s, __fmul_rn(v, v));
    }
    emb_sqr[k] = s;
}

__launch_bounds__(256)
__global__ void k_inpsqr(const float* __restrict__ X, float* __restrict__ S) {
    __shared__ float xs[64][261];
    const int tid = threadIdx.x;
    const int rowBase = blockIdx.x * 64;
    const float4* Xv = (const float4*)(X + (size_t)rowBase * DIM);
#pragma unroll
    for (int it = 0; it < 16; ++it) {
        int lin = it * 256 + tid;
        int r = lin >> 6, c4 = lin & 63;
        float4 v = Xv[lin];
        xs[r][c4 * 4 + 0] = v.x; xs[r][c4 * 4 + 1] = v.y;
        xs[r][c4 * 4 + 2] = v.z; xs[r][c4 * 4 + 3] = v.w;
    }
    __syncthreads();
    if (tid < 64) {
        const float* x = xs[tid];
        float b[2];
#pragma unroll
        for (int h = 0; h < 2; ++h) {
            const float* p = x + h * 128;
            float r[8];
#pragma unroll
            for (int j = 0; j < 8; ++j) r[j] = __fmul_rn(p[j], p[j]);
            for (int i = 8; i < 128; i += 8)
#pragma unroll
                for (int j = 0; j < 8; ++j)
                    r[j] = __fadd_rn(r[j], __fmul_rn(p[i + j], p[i + j]));
            b[h] = __fadd_rn(__fadd_rn(__fadd_rn(r[0], r[1]), __fadd_rn(r[2], r[3])),
                             __fadd_rn(__fadd_rn(r[4], r[5]), __fadd_rn(r[6], r[7])));
        }
        S[rowBase + tid] = __fadd_rn(b[0], b[1]);
    }
}

// ===========================================================================
// k_esplit: E [256][4096] -> ET f32 [4096][256] + EThi/ETlo bf16 [4096][256]
// ===========================================================================
__global__ void k_esplit(const float* __restrict__ E, float* __restrict__ ET,
                         unsigned short* __restrict__ EThi, unsigned short* __restrict__ ETlo) {
    __shared__ float t[32][33];
    const int tx = threadIdx.x & 31, ty = threadIdx.x >> 5;
    const int k0 = blockIdx.x * 32;
    const int d0 = blockIdx.y * 32;
#pragma unroll
    for (int i = 0; i < 32; i += 8)
        t[ty + i][tx] = E[(size_t)(d0 + ty + i) * K_CODES + k0 + tx];
    __syncthreads();
#pragma unroll
    for (int i = 0; i < 32; i += 8) {
        float w = t[tx][ty + i];
        size_t o = (size_t)(k0 + ty + i) * DIM + d0 + tx;
        ET[o] = w;
        unsigned short h = f2bf(w);
        EThi[o] = h;
        ETlo[o] = f2bf(w - bf2f(h));
    }
}

// ===========================================================================
// k_filter v5: 3-term bf16-split MFMA + top-2 + flags.
// Round 9 change: TRIPLE-buffered B + counted vmcnt (T3/T4). Per slice t:
//   top:  issue DMA(t+2) into buf[(t+2)%3]      (2 gload16)
//   mid:  ds_read buf[t%3] + 24 MFMA
//   end:  s_waitcnt vmcnt(2)  [waits DMA(t+1); DMA(t+2) stays in flight]
//         raw s_barrier, sched_barrier(0) fences per 8-phase template.
// Ledger: outstanding at top = 2 -> issue -> 4 -> end-wait retires oldest 2.
// Epilogue emb_sqr loads retire in-order AFTER D(t+1) -> over-drain, safe.
// LDS: Bh@b*16K, Bl@b*16K+8K, b=0..2 (48K); reduce scratch 50688 aliases.
// ===========================================================================
#define FBM 128
#define FBN 128

__launch_bounds__(512, 2)
__global__ void k_filter(const float* __restrict__ X,
                         const unsigned short* __restrict__ EThi,
                         const unsigned short* __restrict__ ETlo,
                         const float* __restrict__ emb_sqr,
                         int* __restrict__ out_idx, int* __restrict__ flagcnt,
                         int* __restrict__ flaglist) {
    __shared__ __align__(16) char lds[50688];

    const int tid = threadIdx.x;
    const int lane = tid & 63;
    const int wid = tid >> 6;
    const int wm = wid & 3;          // row-wave: 32 rows each
    const int wn = wid >> 2;         // col-wave: 64 codes each
    const int rowBase = blockIdx.x * FBM;
    const int l15 = lane & 15, l4 = lane >> 4;

    // ---- prologue: stage X slice per 32-d step, load A-frags to registers
    short8 ah[2][8], al[2][8];
    {
        const int prow = tid >> 2;              // 0..127
        const int pd = (tid & 3) * 8;           // 0,8,16,24
        const int wroff = prow * 128 + ((pd * 2) ^ ((prow & 7) << 4));
#pragma unroll
        for (int ks = 0; ks < 8; ++ks) {
            float4 v0 = *(const float4*)&X[(size_t)(rowBase + prow) * DIM + ks * 32 + pd];
            float4 v1 = *(const float4*)&X[(size_t)(rowBase + prow) * DIM + ks * 32 + pd + 4];
            float f[8] = {v0.x, v0.y, v0.z, v0.w, v1.x, v1.y, v1.z, v1.w};
            unsigned H[4], L[4];
#pragma unroll
            for (int p = 0; p < 4; ++p) {
                float a = f[2 * p], b = f[2 * p + 1];
                unsigned short ha = f2bf(a), hb = f2bf(b);
                float la = a - bf2f(ha), lb = b - bf2f(hb);
                H[p] = (unsigned)ha | ((unsigned)hb << 16);
                L[p] = (unsigned)f2bf(la) | ((unsigned)f2bf(lb) << 16);
            }
            u32x4 Hv = {H[0], H[1], H[2], H[3]};
            u32x4 Lv = {L[0], L[1], L[2], L[3]};
            *(u32x4*)(lds + wroff) = Hv;
            *(u32x4*)(lds + 16384 + wroff) = Lv;
            __syncthreads();
#pragma unroll
            for (int mf = 0; mf < 2; ++mf) {
                int rl = wm * 32 + mf * 16 + l15;
                int off = rl * 128 + ((l4 * 16) ^ ((rl & 7) << 4));
                ah[mf][ks] = *(const short8*)(lds + off);
                al[mf][ks] = *(const short8*)(lds + 16384 + off);
            }
            __syncthreads();   // drains vmcnt/lgkm -> clean counter slate
        }
    }

    // ---- per-(mf,r) top-2 state
    float v1r[8], v2r[8];
    int i1r[8];
#pragma unroll
    for (int s = 0; s < 8; ++s) { v1r[s] = FLT_MAX; v2r[s] = FLT_MAX; i1r[s] = 0; }

    // ---- gload_lds source geometry (per-lane, loop-invariant):
    //   r = wid*16 + (lane>>2),  c' = lane&3,  c = c' ^ ((r>>1)&3)  (rule #21)
    const int gr = (wid << 4) + (lane >> 2);
    const int gc = (lane & 3) ^ ((lane >> 3) & 3);
    const size_t goff = (size_t)gr * DIM + gc * 8;      // u16 elements

    // ---- B-frag read offsets (swizzled), hoisted
    int boff[4];
#pragma unroll
    for (int nf = 0; nf < 4; ++nf) {
        int cl = wn * 64 + nf * 16 + l15;
        boff[nf] = cl * 64 + ((l4 ^ ((cl >> 1) & 3)) << 4);
    }

    // ---- stage slices 0 (buf0) and 1 (buf1)
    gload16(EThi + goff, lds + (wid << 10));
    gload16(ETlo + goff, lds + 8192 + (wid << 10));
    gload16(EThi + 32 + goff, lds + 16384 + (wid << 10));
    gload16(ETlo + 32 + goff, lds + 16384 + 8192 + (wid << 10));
    asm volatile("s_waitcnt vmcnt(2)" ::: "memory");   // slice 0 landed
    __builtin_amdgcn_sched_barrier(0);
    __builtin_amdgcn_s_barrier();
    __builtin_amdgcn_sched_barrier(0);

    int bcur = 0;   // buffer holding slice t; rotates 0->1->2->0
    for (int ct = 0; ct < K_CODES / FBN; ++ct) {   // 32 code tiles
        f32x4 acc[2][4];
#pragma unroll
        for (int mf = 0; mf < 2; ++mf)
#pragma unroll
            for (int nf = 0; nf < 4; ++nf) acc[mf][nf] = (f32x4)0.f;

#pragma unroll
        for (int ks = 0; ks < 8; ++ks) {
            const int t = ct * 8 + ks;
            // ---- top: issue DMA(t+2) into buf[(t+2)%3] (readers done at t-1)
            const int tp = (t + 2 < 256) ? t + 2 : 255;
            const int bw = (bcur == 0) ? 2 : bcur - 1;   // (bcur+2)%3
            char* nb = lds + (bw << 14) + (wid << 10);
            const size_t go = (size_t)(tp >> 3) * (FBN * DIM) + (size_t)(tp & 7) * 32 + goff;
            gload16(EThi + go, nb);
            gload16(ETlo + go, nb + 8192);
            __builtin_amdgcn_sched_barrier(0);
            // ---- mid: consume buf[bcur]
            const char* base = lds + (bcur << 14);
#pragma unroll
            for (int nf = 0; nf < 4; ++nf) {
                short8 bh = *(const short8*)(base + boff[nf]);
                short8 bl = *(const short8*)(base + 8192 + boff[nf]);
#pragma unroll
                for (int mf = 0; mf < 2; ++mf) {
                    acc[mf][nf] = __builtin_amdgcn_mfma_f32_16x16x32_bf16(ah[mf][ks], bh, acc[mf][nf], 0, 0, 0);
                    acc[mf][nf] = __builtin_amdgcn_mfma_f32_16x16x32_bf16(ah[mf][ks], bl, acc[mf][nf], 0, 0, 0);
                    acc[mf][nf] = __builtin_amdgcn_mfma_f32_16x16x32_bf16(al[mf][ks], bh, acc[mf][nf], 0, 0, 0);
                }
            }
            __builtin_amdgcn_sched_barrier(0);
            // ---- end: wait DMA(t+1) only; DMA(t+2) stays in flight
            asm volatile("s_waitcnt vmcnt(2)" ::: "memory");
            __builtin_amdgcn_sched_barrier(0);
            __builtin_amdgcn_s_barrier();
            __builtin_amdgcn_sched_barrier(0);
            bcur = (bcur == 2) ? 0 : bcur + 1;
        }

        // ---- epilogue: approx distance d~ = emb_sqr - 2*M; top-2 update.
        // (global es loads retire in-order after D(t+1): over-drain, safe)
#pragma unroll
        for (int nf = 0; nf < 4; ++nf) {
            int col = ct * FBN + wn * 64 + nf * 16 + l15;
            float esv = emb_sqr[col];
#pragma unroll
            for (int mf = 0; mf < 2; ++mf)
#pragma unroll
                for (int r = 0; r < 4; ++r) {
                    float da = __fmaf_rn(-2.f, acc[mf][nf][r], esv);
                    int s = mf * 4 + r;
                    if (da < v1r[s]) { v2r[s] = v1r[s]; v1r[s] = da; i1r[s] = col; }
                    else if (da < v2r[s]) v2r[s] = da;
                }
        }
    }

    // ---- cross-entry reduce: per row 32 entries (2 col-waves x 16 lanes)
    __syncthreads();   // full drain (incl. tail DMAs) before LDS reuse
    float* v1s = (float*)lds;                  // [128][33] 16.9 KB
    int*   i1s = (int*)(lds + 16896);
    float* v2s = (float*)(lds + 33792);
#pragma unroll
    for (int mf = 0; mf < 2; ++mf)
#pragma unroll
        for (int r = 0; r < 4; ++r) {
            int rl = wm * 32 + mf * 16 + l4 * 4 + r;
            int e = wn * 16 + l15;
            v1s[rl * 33 + e] = v1r[mf * 4 + r];
            i1s[rl * 33 + e] = i1r[mf * 4 + r];
            v2s[rl * 33 + e] = v2r[mf * 4 + r];
        }
    __syncthreads();
    if (tid < FBM) {
        float bv1 = v1s[tid * 33], bv2 = v2s[tid * 33];
        int bi = i1s[tid * 33];
#pragma unroll
        for (int e = 1; e < 32; ++e) {
            float v = v1s[tid * 33 + e], w = v2s[tid * 33 + e];
            int ix = i1s[tid * 33 + e];
            if (v < bv1 || (v == bv1 && ix < bi)) {
                bv2 = fminf(bv1, w); bv1 = v; bi = ix;
            } else {
                bv2 = fminf(bv2, v);
            }
        }
        out_idx[rowBase + tid] = bi;
        if (bv2 - bv1 < MARGIN) {
            int p = atomicAdd(flagcnt, 1);
            flaglist[p] = rowBase + tid;
        }
    }
}

// ===========================================================================
// k_fixup32: np-bit-exact full rescan for flagged rows (round-3 arithmetic)
// ===========================================================================
__launch_bounds__(256)
__global__ void k_fixup32(const float* __restrict__ X, const float* __restrict__ E,
                          const float* __restrict__ emb_sqr, const float* __restrict__ S,
                          const int* __restrict__ flagcnt, const int* __restrict__ flaglist,
                          int* __restrict__ out_idx) {
    __shared__ float xs[DIM];
    __shared__ float rv[256];
    __shared__ int ri[256];
    const int tid = threadIdx.x;
    const int cnt = *flagcnt;
    for (int f = blockIdx.x; f < cnt; f += gridDim.x) {
        const int row = flaglist[f];
        xs[tid] = X[(size_t)row * DIM + tid];
        __syncthreads();
        const float Sr = S[row];
        float acc[16];
#pragma unroll
        for (int j = 0; j < 16; ++j) acc[j] = 0.f;
        for (int d = 0; d < DIM; ++d) {
            float xv = xs[d];
            const float* Ed = &E[(size_t)d * K_CODES + tid];
#pragma unroll
            for (int j = 0; j < 16; ++j)
                acc[j] = __fmaf_rn(xv, Ed[j * 256], acc[j]);
        }
        float bv = FLT_MAX;
        int bk = 0;
#pragma unroll
        for (int j = 0; j < 16; ++j) {
            int k = tid + 256 * j;   // ascending within thread
            float dist = __fadd_rn(__fsub_rn(Sr, __fmul_rn(2.f, acc[j])), emb_sqr[k]);
            if (dist < bv) { bv = dist; bk = k; }
        }
        rv[tid] = bv; ri[tid] = bk;
        __syncthreads();
        for (int s = 128; s > 0; s >>= 1) {
            if (tid < s) {
                float v = rv[tid + s]; int k2 = ri[tid + s];
                if (v < rv[tid] || (v == rv[tid] && k2 < ri[tid])) { rv[tid] = v; ri[tid] = k2; }
            }
            __syncthreads();
        }
        if (tid == 0) out_idx[row] = ri[0];
        __syncthreads();
    }
}

// ===========================================================================
// Fallback fp32 argmin (round-4, validated) for small-ws case
// ===========================================================================
#define BM 64
#define BN 256
#define DCHUNK 8
#define XS_LD 260

#define FMA8(a, b1, b2, accrow)                                       \
    do {                                                              \
        accrow[0] = __fmaf_rn((a), (b1).x, accrow[0]);                \
        accrow[1] = __fmaf_rn((a), (b1).y, accrow[1]);                \
        accrow[2] = __fmaf_rn((a), (b1).z, accrow[2]);                \
        accrow[3] = __fmaf_rn((a), (b1).w, accrow[3]);                \
        accrow[4] = __fmaf_rn((a), (b2).x, accrow[4]);                \
        accrow[5] = __fmaf_rn((a), (b2).y, accrow[5]);                \
        accrow[6] = __fmaf_rn((a), (b2).z, accrow[6]);                \
        accrow[7] = __fmaf_rn((a), (b2).w, accrow[7]);                \
    } while (0)

__launch_bounds__(256, 2)
__global__ void k_argmin(const float* __restrict__ X, const float* __restrict__ E,
                         const float* __restrict__ emb_sqr, const float* __restrict__ S,
                         int* __restrict__ out_idx) {
    __shared__ float Xs[BM][XS_LD];
    __shared__ float Es[DCHUNK][BN];
    const int tid = threadIdx.x;
    const int tx = tid & 31;
    const int ty = tid >> 5;
    const int rowBase = blockIdx.x * BM;
    const int r0 = ty * 8;
    {
        const float4* Xv = (const float4*)(X + (size_t)rowBase * DIM);
#pragma unroll
        for (int it = 0; it < 16; ++it) {
            int lin = it * 256 + tid;
            int r = lin >> 6, c4 = lin & 63;
            float4 v = Xv[lin];
            *(float4*)&Xs[r][c4 * 4] = v;
        }
    }
    float Srow[8];
#pragma unroll
    for (int i = 0; i < 8; ++i) Srow[i] = S[rowBase + r0 + i];
    float best[8];
    int bidx[8];
#pragma unroll
    for (int i = 0; i < 8; ++i) { best[i] = FLT_MAX; bidx[i] = 0; }
    for (int ct = 0; ct < K_CODES / BN; ++ct) {
        const int cbase = ct * BN;
        float acc[8][8];
#pragma unroll
        for (int i = 0; i < 8; ++i)
#pragma unroll
            for (int j = 0; j < 8; ++j) acc[i][j] = 0.f;
        for (int dc = 0; dc < DIM / DCHUNK; ++dc) {
            __syncthreads();
#pragma unroll
            for (int it = 0; it < 2; ++it) {
                int lin = it * 256 + tid;
                int r = lin >> 6, c4 = lin & 63;
                float4 v = *(const float4*)&E[(size_t)(dc * DCHUNK + r) * K_CODES + cbase + c4 * 4];
                *(float4*)&Es[r][c4 * 4] = v;
            }
            __syncthreads();
            const int db = dc * DCHUNK;
#pragma unroll
            for (int kk = 0; kk < DCHUNK; kk += 4) {
                float4 a4[8];
#pragma unroll
                for (int i = 0; i < 8; ++i)
                    a4[i] = *(const float4*)&Xs[r0 + i][db + kk];
                float4 bA[4], bB[4];
#pragma unroll
                for (int t = 0; t < 4; ++t) {
                    bA[t] = *(const float4*)&Es[kk + t][tx * 4];
                    bB[t] = *(const float4*)&Es[kk + t][128 + tx * 4];
                }
#pragma unroll
                for (int i = 0; i < 8; ++i) {
                    float4 av = a4[i];
                    FMA8(av.x, bA[0], bB[0], acc[i]);
                    FMA8(av.y, bA[1], bB[1], acc[i]);
                    FMA8(av.z, bA[2], bB[2], acc[i]);
                    FMA8(av.w, bA[3], bB[3], acc[i]);
                }
            }
        }
        float es[8];
#pragma unroll
        for (int j = 0; j < 4; ++j) es[j]     = emb_sqr[cbase + tx * 4 + j];
#pragma unroll
        for (int j = 0; j < 4; ++j) es[4 + j] = emb_sqr[cbase + 128 + tx * 4 + j];
#pragma unroll
        for (int i = 0; i < 8; ++i) {
#pragma unroll
            for (int j = 0; j < 8; ++j) {
                float d = __fadd_rn(__fsub_rn(Srow[i], __fmul_rn(2.f, acc[i][j])), es[j]);
                int cidx = cbase + ((j < 4) ? (tx * 4 + j) : (128 + tx * 4 + (j - 4)));
                if (d < best[i]) { best[i] = d; bidx[i] = cidx; }
            }
        }
    }
    __syncthreads();
    float* rv1 = &Xs[0][0];
    int*   ri1 = (int*)(rv1 + 2048);
#pragma unroll
    for (int i = 0; i < 8; ++i) {
        rv1[(r0 + i) * 32 + tx] = best[i];
        ri1[(r0 + i) * 32 + tx] = bidx[i];
    }
    __syncthreads();
    if (tid < BM) {
        float bv = rv1[tid * 32];
        int bi = ri1[tid * 32];
#pragma unroll
        for (int t = 1; t < 32; ++t) {
            float v = rv1[tid * 32 + t];
            int ix = ri1[tid * 32 + t];
            if (v < bv || (v == bv && ix < bi)) { bv = v; bi = ix; }
        }
        out_idx[rowBase + tid] = bi;
    }
}

// ===========================================================================
// Gather + loss
// ===========================================================================
__global__ void k_gather_et(const float* __restrict__ X, const float* __restrict__ ET,
                            const int* __restrict__ idx, float* __restrict__ out,
                            float* __restrict__ partials) {
    const int tid = threadIdx.x;
    const int total4 = N_ROWS * DIM / 4;
    float lsum = 0.f;
    for (int g = blockIdx.x * 256 + tid; g < total4; g += 2048 * 256) {
        int row = g >> 6;
        int d4 = g & 63;
        int k = idx[row];
        float4 z = *(const float4*)&X[(size_t)g * 4];
        float4 q = *(const float4*)&ET[(size_t)k * DIM + d4 * 4];
        float dx = __fsub_rn(q.x, z.x), dy = __fsub_rn(q.y, z.y);
        float dz = __fsub_rn(q.z, z.z), dw = __fsub_rn(q.w, z.w);
        float4 o;
        o.x = __fadd_rn(z.x, dx); o.y = __fadd_rn(z.y, dy);
        o.z = __fadd_rn(z.z, dz); o.w = __fadd_rn(z.w, dw);
        *(float4*)&out[(size_t)g * 4] = o;
        lsum += dx * dx + dy * dy + dz * dz + dw * dw;
    }
    __shared__ float red[256];
    red[tid] = lsum;
    __syncthreads();
    for (int s = 128; s > 0; s >>= 1) {
        if (tid < s) red[tid] += red[tid + s];
        __syncthreads();
    }
    if (tid == 0) partials[blockIdx.x] = red[0];
}

__global__ void k_gather_e(const float* __restrict__ X, const float* __restrict__ E,
                           const int* __restrict__ idx, float* __restrict__ out,
                           float* __restrict__ partials) {
    const int tid = threadIdx.x;
    const int total4 = N_ROWS * DIM / 4;
    float lsum = 0.f;
    for (int g = blockIdx.x * 256 + tid; g < total4; g += 2048 * 256) {
        int row = g >> 6;
        int d4 = g & 63;
        int k = idx[row];
        float4 z = *(const float4*)&X[(size_t)g * 4];
        float4 q;
        q.x = E[(size_t)(d4 * 4 + 0) * K_CODES + k];
        q.y = E[(size_t)(d4 * 4 + 1) * K_CODES + k];
        q.z = E[(size_t)(d4 * 4 + 2) * K_CODES + k];
        q.w = E[(size_t)(d4 * 4 + 3) * K_CODES + k];
        float dx = __fsub_rn(q.x, z.x), dy = __fsub_rn(q.y, z.y);
        float dz = __fsub_rn(q.z, z.z), dw = __fsub_rn(q.w, z.w);
        float4 o;
        o.x = __fadd_rn(z.x, dx); o.y = __fadd_rn(z.y, dy);
        o.z = __fadd_rn(z.z, dz); o.w = __fadd_rn(z.w, dw);
        *(float4*)&out[(size_t)g * 4] = o;
        lsum += dx * dx + dy * dy + dz * dz + dw * dw;
    }
    __shared__ float red[256];
    red[tid] = lsum;
    __syncthreads();
    for (int s = 128; s > 0; s >>= 1) {
        if (tid < s) red[tid] += red[tid + s];
        __syncthreads();
    }
    if (tid == 0) partials[blockIdx.x] = red[0];
}

__global__ void k_loss(const float* __restrict__ partials, float* __restrict__ out_loss) {
    __shared__ float red[256];
    const int tid = threadIdx.x;
    float s = 0.f;
    for (int i = tid; i < 2048; i += 256) s += partials[i];
    red[tid] = s;
    __syncthreads();
    for (int st = 128; st > 0; st >>= 1) {
        if (tid < st) red[tid] += red[tid + st];
        __syncthreads();
    }
    if (tid == 0) out_loss[0] = 1.25f * red[0] / 16777216.0f;
}

// ===========================================================================
extern "C" void kernel_launch(void* const* d_in, const int* in_sizes, int n_in,
                              void* d_out, int out_size, void* d_ws, size_t ws_size,
                              hipStream_t stream) {
    (void)in_sizes; (void)n_in; (void)out_size;
    const float* X = (const float*)d_in[0];   // z_latents [65536][256]
    const float* E = (const float*)d_in[1];   // embeddings [256][4096]
    float* out = (float*)d_out;

    char* ws = (char*)d_ws;
    int*   idx      = (int*)ws;                         // @0        256 KB
    float* emb_sqr  = (float*)(ws + 262144);            // @262144   16 KB
    float* S        = (float*)(ws + 278528);            // @278528   256 KB
    float* partials = (float*)(ws + 540672);            // @540672   8 KB
    int*   flagcnt  = (int*)(ws + 548864);              // @548864   256 B
    int*   flaglist = (int*)(ws + 549120);              // @549120   256 KB
    float* ET       = (float*)(ws + 811264);            // @811264   4 MB
    unsigned short* EThi = (unsigned short*)(ws + 5005568);  // 2 MB
    unsigned short* ETlo = (unsigned short*)(ws + 7102720);  // 2 MB
    const size_t WS_NEED = 9199872;

    k_embsqr<<<K_CODES / 256, 256, 0, stream>>>(E, emb_sqr);
    k_inpsqr<<<N_ROWS / 64, 256, 0, stream>>>(X, S);

    if (ws_size >= WS_NEED) {
        hipMemsetAsync(flagcnt, 0, 4, stream);
        k_esplit<<<dim3(K_CODES / 32, DIM / 32), 256, 0, stream>>>(E, ET, EThi, ETlo);
        k_filter<<<N_ROWS / FBM, 512, 0, stream>>>(X, EThi, ETlo, emb_sqr, idx, flagcnt, flaglist);
        k_fixup32<<<512, 256, 0, stream>>>(X, E, emb_sqr, S, flagcnt, flaglist, idx);
        k_gather_et<<<2048, 256, 0, stream>>>(X, ET, idx, out, partials);
    } else {
        k_argmin<<<N_ROWS / BM, 256, 0, stream>>>(X, E, emb_sqr, S, idx);
        k_gather_e<<<2048, 256, 0, stream>>>(X, E, idx, out, partials);
    }
    k_loss<<<1, 256, 0, stream>>>(partials, out + (size_t)N_ROWS * DIM);
}